// Round 1
// baseline (938.402 us; speedup 1.0000x reference)
//
#include <hip/hip_runtime.h>

// ---------------- sizes (fixed by the reference) ----------------
#define IN_CH   16
#define H_G     128

// ---------------- CSR build ----------------
__global__ void init_kernel(float* deg, int* cnt, int* fill, int n) {
  int i = blockIdx.x * blockDim.x + threadIdx.x;
  if (i < n) { deg[i] = 1.0f; cnt[i] = 0; fill[i] = 0; }
}

__global__ void count_kernel(const int* __restrict__ ei, const float* __restrict__ ew,
                             float* deg, int* cnt, int E) {
  int e = blockIdx.x * blockDim.x + threadIdx.x;
  if (e < E) {
    int dst = ei[E + e];
    atomicAdd(&deg[dst], ew[e]);
    atomicAdd(&cnt[dst], 1);
  }
}

__global__ void dinv_kernel(const float* __restrict__ deg, float* __restrict__ dinv, int n) {
  int i = blockIdx.x * blockDim.x + threadIdx.x;
  if (i < n) {
    float d = deg[i];
    dinv[i] = (d > 0.f) ? rsqrtf(d) : 0.f;
  }
}

// single-block exclusive scan over cnt -> row_ptr (n+1 entries)
__global__ __launch_bounds__(1024) void scan_kernel(const int* __restrict__ cnt,
                                                    int* __restrict__ row_ptr, int n) {
  __shared__ int sh[1024];
  __shared__ int carry_s;
  if (threadIdx.x == 0) carry_s = 0;
  __syncthreads();
  int nchunks = (n + 1023) / 1024;
  for (int c = 0; c < nchunks; ++c) {
    int i = c * 1024 + threadIdx.x;
    int v = (i < n) ? cnt[i] : 0;
    sh[threadIdx.x] = v;
    __syncthreads();
    for (int off = 1; off < 1024; off <<= 1) {
      int t = (threadIdx.x >= off) ? sh[threadIdx.x - off] : 0;
      __syncthreads();
      sh[threadIdx.x] += t;
      __syncthreads();
    }
    int incl = sh[threadIdx.x];
    int carry = carry_s;
    if (i < n) row_ptr[i] = carry + incl - v;
    __syncthreads();
    if (threadIdx.x == 1023) carry_s = carry + incl;
    __syncthreads();
  }
  if (threadIdx.x == 0) row_ptr[n] = carry_s;
}

__global__ void scatter_kernel(const int* __restrict__ ei, const float* __restrict__ ew,
                               const float* __restrict__ dinv, const int* __restrict__ row_ptr,
                               int* fill, int* __restrict__ csr_src, float* __restrict__ csr_w,
                               int E) {
  int e = blockIdx.x * blockDim.x + threadIdx.x;
  if (e < E) {
    int src = ei[e];
    int dst = ei[E + e];
    int pos = row_ptr[dst] + atomicAdd(&fill[dst], 1);
    csr_src[pos] = src;
    csr_w[pos]   = ew[e] * dinv[src];   // dinv[dst] factored out in spmm
  }
}

// ---------------- pull-based SpMM: out[v] = dinv[v]*sum_e w*h[src] + dinv[v]^2*h[v] ----------------
template<int C>
__global__ __launch_bounds__(256) void spmm_kernel(
    const float* __restrict__ h, const float* __restrict__ dinv,
    const int* __restrict__ row_ptr, const int* __restrict__ csr_src,
    const float* __restrict__ csr_w, float* __restrict__ out, int n) {
  constexpr int NPB = 256 / C;
  int lane = threadIdx.x % C;
  int v = blockIdx.x * NPB + threadIdx.x / C;
  if (v >= n) return;
  int beg = row_ptr[v], end = row_ptr[v + 1];
  float sum = 0.f;
  for (int e = beg; e < end; ++e) {
    int s   = csr_src[e];
    float w = csr_w[e];
    sum += w * h[(size_t)s * C + lane];
  }
  float dv   = dinv[v];
  float self = h[(size_t)v * C + lane];
  out[(size_t)v * C + lane] = dv * sum + dv * dv * self;
}

// ---------------- dense GEMM: Y[n,128] = relu(X[n,K] @ W[K,128] + b) ----------------
template<int K>
__global__ __launch_bounds__(256) void gemm_kernel(
    const float* __restrict__ X, const float* __restrict__ W,
    const float* __restrict__ bias, float* __restrict__ Y,
    int n, int do_relu) {
  __shared__ float Ws[K][128];
  __shared__ float Xs[32][K];
  const int tid = threadIdx.x;
  const int row0 = blockIdx.x * 32;

  for (int i = tid * 4; i < K * 128; i += 1024) {
    *(float4*)&Ws[0][i] = *(const float4*)&W[i];
  }
  for (int i = tid * 4; i < 32 * K; i += 1024) {
    int r = i / K, k = i % K;
    int rr = row0 + r;
    float4 v = make_float4(0.f, 0.f, 0.f, 0.f);
    if (rr < n) v = *(const float4*)&X[(size_t)rr * K + k];
    *(float4*)&Xs[r][k] = v;
  }
  __syncthreads();

  const int tc = (tid & 31) * 4;   // column group (0..124)
  const int tr = (tid >> 5) * 4;   // row group (0..28)
  float acc[4][4] = {};

  for (int k = 0; k < K; k += 4) {
    float4 xv[4];
#pragma unroll
    for (int r = 0; r < 4; ++r) xv[r] = *(const float4*)&Xs[tr + r][k];
    float4 wv[4];
#pragma unroll
    for (int kk = 0; kk < 4; ++kk) wv[kk] = *(const float4*)&Ws[k + kk][tc];
#pragma unroll
    for (int r = 0; r < 4; ++r) {
      float xr[4] = {xv[r].x, xv[r].y, xv[r].z, xv[r].w};
#pragma unroll
      for (int kk = 0; kk < 4; ++kk) {
        acc[r][0] += xr[kk] * wv[kk].x;
        acc[r][1] += xr[kk] * wv[kk].y;
        acc[r][2] += xr[kk] * wv[kk].z;
        acc[r][3] += xr[kk] * wv[kk].w;
      }
    }
  }

  float4 bv = *(const float4*)&bias[tc];
#pragma unroll
  for (int r = 0; r < 4; ++r) {
    int rr = row0 + tr + r;
    if (rr < n) {
      float4 o;
      o.x = acc[r][0] + bv.x;
      o.y = acc[r][1] + bv.y;
      o.z = acc[r][2] + bv.z;
      o.w = acc[r][3] + bv.w;
      if (do_relu) {
        o.x = fmaxf(o.x, 0.f); o.y = fmaxf(o.y, 0.f);
        o.z = fmaxf(o.z, 0.f); o.w = fmaxf(o.w, 0.f);
      }
      *(float4*)&Y[(size_t)rr * 128 + tc] = o;
    }
  }
}

// ---------------- mean pool per graph (batch sorted) ----------------
__global__ __launch_bounds__(128) void pool_kernel(
    const float* __restrict__ h, const int* __restrict__ batch,
    float* __restrict__ gp, int n) {
  int g = blockIdx.x, c = threadIdx.x;
  int lo = 0, hi = n;
  while (lo < hi) { int mid = (lo + hi) >> 1; if (batch[mid] < g) lo = mid + 1; else hi = mid; }
  int start = lo;
  lo = start; hi = n;
  while (lo < hi) { int mid = (lo + hi) >> 1; if (batch[mid] < g + 1) lo = mid + 1; else hi = mid; }
  int end = lo;
  float s = 0.f;
  for (int v = start; v < end; ++v) s += h[(size_t)v * 128 + c];
  float cnt = (float)(end - start);
  gp[g * 128 + c] = s / fmaxf(cnt, 1.0f);
}

// ---------------- context MLP: 3 layers, relu each ----------------
__global__ __launch_bounds__(128) void ctx_kernel(
    const float* __restrict__ xc,
    const float* __restrict__ W0, const float* __restrict__ b0,
    const float* __restrict__ W1, const float* __restrict__ b1,
    const float* __restrict__ W2, const float* __restrict__ b2,
    float* __restrict__ out) {
  int g = blockIdx.x, c = threadIdx.x;
  __shared__ float buf[128];
  __shared__ float xin[16];
  if (c < 16) xin[c] = xc[g * 16 + c];
  __syncthreads();
  float a = b0[c];
#pragma unroll
  for (int k = 0; k < 16; ++k) a += xin[k] * W0[k * 128 + c];
  a = fmaxf(a, 0.f);
  buf[c] = a;
  __syncthreads();
  float a1 = b1[c];
  for (int k = 0; k < 128; ++k) a1 += buf[k] * W1[k * 128 + c];
  a1 = fmaxf(a1, 0.f);
  __syncthreads();
  buf[c] = a1;
  __syncthreads();
  float a2 = b2[c];
  for (int k = 0; k < 128; ++k) a2 += buf[k] * W2[k * 128 + c];
  a2 = fmaxf(a2, 0.f);
  out[g * 128 + c] = a2;
}

// ---------------- head: z = [g, c]; relu(z@fW0), relu(@fW1), @fW2 ----------------
__global__ __launch_bounds__(128) void head_kernel(
    const float* __restrict__ gp, const float* __restrict__ ctx,
    const float* __restrict__ W0, const float* __restrict__ b0,
    const float* __restrict__ W1, const float* __restrict__ b1,
    const float* __restrict__ W2, const float* __restrict__ b2,
    float* __restrict__ out) {
  int g = blockIdx.x, c = threadIdx.x;
  __shared__ float z[256];
  __shared__ float buf[128];
  z[c]       = gp[g * 128 + c];
  z[128 + c] = ctx[g * 128 + c];
  __syncthreads();
  float a = b0[c];
  for (int k = 0; k < 256; ++k) a += z[k] * W0[k * 128 + c];
  a = fmaxf(a, 0.f);
  buf[c] = a;
  __syncthreads();
  float a1 = b1[c];
  for (int k = 0; k < 128; ++k) a1 += buf[k] * W1[k * 128 + c];
  a1 = fmaxf(a1, 0.f);
  __syncthreads();
  buf[c] = a1;
  __syncthreads();
  float a2 = b2[c];
  for (int k = 0; k < 128; ++k) a2 += buf[k] * W2[k * 128 + c];
  out[g * 128 + c] = a2;
}

// ---------------- launch ----------------
extern "C" void kernel_launch(void* const* d_in, const int* in_sizes, int n_in,
                              void* d_out, int out_size, void* d_ws, size_t ws_size,
                              hipStream_t stream) {
  const float* x     = (const float*)d_in[0];
  const float* xc    = (const float*)d_in[1];
  const int*   ei    = (const int*)d_in[2];
  const int*   batch = (const int*)d_in[3];
  const float* ew    = (const float*)d_in[4];
  const float* gW[4] = {(const float*)d_in[5], (const float*)d_in[7], (const float*)d_in[9],  (const float*)d_in[11]};
  const float* gb[4] = {(const float*)d_in[6], (const float*)d_in[8], (const float*)d_in[10], (const float*)d_in[12]};
  const float* cW0 = (const float*)d_in[13]; const float* cb0 = (const float*)d_in[14];
  const float* cW1 = (const float*)d_in[15]; const float* cb1 = (const float*)d_in[16];
  const float* cW2 = (const float*)d_in[17]; const float* cb2 = (const float*)d_in[18];
  const float* fW0 = (const float*)d_in[19]; const float* fb0 = (const float*)d_in[20];
  const float* fW1 = (const float*)d_in[21]; const float* fb1 = (const float*)d_in[22];
  const float* fW2 = (const float*)d_in[23]; const float* fb2 = (const float*)d_in[24];
  float* out = (float*)d_out;

  const int N = in_sizes[3];          // nodes (from batch)
  const int E = in_sizes[4];          // edges (from edge_weight)
  const int G = in_sizes[1] / IN_CH;  // graphs

  // workspace carve-out
  char* p = (char*)d_ws;
  auto alloc = [&](size_t bytes) { char* r = p; p += (bytes + 255) & ~(size_t)255; return r; };
  float* deg     = (float*)alloc((size_t)N * 4);
  float* dinv    = (float*)alloc((size_t)N * 4);
  int*   cnt     = (int*)  alloc((size_t)N * 4);
  int*   fill    = (int*)  alloc((size_t)N * 4);
  int*   row_ptr = (int*)  alloc((size_t)(N + 1) * 4);
  int*   csr_src = (int*)  alloc((size_t)E * 4);
  float* csr_w   = (float*)alloc((size_t)E * 4);
  float* A       = (float*)alloc((size_t)N * 128 * 4);  // agg buffer (also holds 16-ch agg)
  float* H       = (float*)alloc((size_t)N * 128 * 4);  // hidden state
  float* gp      = (float*)alloc((size_t)G * 128 * 4);
  float* cb      = (float*)alloc((size_t)G * 128 * 4);

  int nbN = (N + 255) / 256;
  int nbE = (E + 255) / 256;

  // CSR build
  init_kernel<<<nbN, 256, 0, stream>>>(deg, cnt, fill, N);
  count_kernel<<<nbE, 256, 0, stream>>>(ei, ew, deg, cnt, E);
  dinv_kernel<<<nbN, 256, 0, stream>>>(deg, dinv, N);
  scan_kernel<<<1, 1024, 0, stream>>>(cnt, row_ptr, N);
  scatter_kernel<<<nbE, 256, 0, stream>>>(ei, ew, dinv, row_ptr, fill, csr_src, csr_w, E);

  // layer 0: aggregate 16ch then transform 16->128
  spmm_kernel<16><<<(N + 15) / 16, 256, 0, stream>>>(x, dinv, row_ptr, csr_src, csr_w, A, N);
  gemm_kernel<16><<<(N + 31) / 32, 256, 0, stream>>>(A, gW[0], gb[0], H, N, 1);

  // layers 1..3: aggregate 128ch then transform 128->128
  for (int l = 1; l < 4; ++l) {
    spmm_kernel<128><<<(N + 1) / 2, 256, 0, stream>>>(H, dinv, row_ptr, csr_src, csr_w, A, N);
    gemm_kernel<128><<<(N + 31) / 32, 256, 0, stream>>>(A, gW[l], gb[l], H, N, 1);
  }

  // pool + context + head
  pool_kernel<<<G, 128, 0, stream>>>(H, batch, gp, N);
  ctx_kernel<<<G, 128, 0, stream>>>(xc, cW0, cb0, cW1, cb1, cW2, cb2, cb);
  head_kernel<<<G, 128, 0, stream>>>(gp, cb, fW0, fb0, fW1, fb1, fW2, fb2, out);
}

// Round 2
// 467.472 us; speedup vs baseline: 2.0074x; 2.0074x over previous
//
#include <hip/hip_runtime.h>

typedef __attribute__((ext_vector_type(8))) short short8;
typedef __attribute__((ext_vector_type(4))) float f32x4;

#define IN_CH 16

// ---------- helpers ----------
__device__ inline unsigned int bf16_rne(float f) {
  unsigned int u = __float_as_uint(f);
  unsigned int r = u + 0x7fffu + ((u >> 16) & 1u);
  return r >> 16;
}
__device__ inline float bf16lo(unsigned int g) { return __uint_as_float(g << 16); }
__device__ inline float bf16hi(unsigned int g) { return __uint_as_float(g & 0xffff0000u); }
__device__ inline short8 as_short8(uint4 u) {
  union { uint4 u; short8 s; } cv; cv.u = u; return cv.s;
}

// ---------- CSR build ----------
__global__ void init_kernel(float* deg, int* cnt, int* fill, int n) {
  int i = blockIdx.x * blockDim.x + threadIdx.x;
  if (i < n) { deg[i] = 1.0f; cnt[i] = 0; fill[i] = 0; }
}

__global__ void count_kernel(const int* __restrict__ ei, const float* __restrict__ ew,
                             float* deg, int* cnt, int E) {
  int e = blockIdx.x * blockDim.x + threadIdx.x;
  if (e < E) {
    int dst = ei[E + e];
    atomicAdd(&deg[dst], ew[e]);
    atomicAdd(&cnt[dst], 1);
  }
}

__global__ void dinv_kernel(const float* __restrict__ deg, float* __restrict__ dinv, int n) {
  int i = blockIdx.x * blockDim.x + threadIdx.x;
  if (i < n) {
    float d = deg[i];
    dinv[i] = (d > 0.f) ? rsqrtf(d) : 0.f;
  }
}

// hierarchical exclusive scan: per-block (256) -> top -> add
__global__ __launch_bounds__(256) void scan_block_kernel(const int* __restrict__ cnt,
                                                         int* __restrict__ row_ptr,
                                                         int* __restrict__ blocksum, int n) {
  int i = blockIdx.x * 256 + threadIdx.x;
  int v = (i < n) ? cnt[i] : 0;
  int lane = threadIdx.x & 63;
  int incl = v;
#pragma unroll
  for (int off = 1; off < 64; off <<= 1) {
    int t = __shfl_up(incl, off);
    if (lane >= off) incl += t;
  }
  __shared__ int wsum[4];
  int w = threadIdx.x >> 6;
  if (lane == 63) wsum[w] = incl;
  __syncthreads();
  if (threadIdx.x == 0) {
    int a = wsum[0], b = wsum[1], c = wsum[2], d = wsum[3];
    wsum[0] = 0; wsum[1] = a; wsum[2] = a + b; wsum[3] = a + b + c;
    blocksum[blockIdx.x] = a + b + c + d;
  }
  __syncthreads();
  int excl = incl - v + wsum[w];
  if (i < n) row_ptr[i] = excl;
}

__global__ __launch_bounds__(256) void scan_top_kernel(int* __restrict__ blocksum, int nb) {
  int v = (threadIdx.x < nb) ? blocksum[threadIdx.x] : 0;
  int lane = threadIdx.x & 63;
  int incl = v;
#pragma unroll
  for (int off = 1; off < 64; off <<= 1) {
    int t = __shfl_up(incl, off);
    if (lane >= off) incl += t;
  }
  __shared__ int wsum[4];
  int w = threadIdx.x >> 6;
  if (lane == 63) wsum[w] = incl;
  __syncthreads();
  if (threadIdx.x == 0) {
    int a = wsum[0], b = wsum[1], c = wsum[2];
    wsum[3] = a + b + c; wsum[2] = a + b; wsum[1] = a; wsum[0] = 0;
  }
  __syncthreads();
  int excl = incl - v + wsum[w];
  if (threadIdx.x < nb) blocksum[threadIdx.x] = excl;
}

__global__ __launch_bounds__(256) void scan_add_kernel(int* __restrict__ row_ptr,
                                                       const int* __restrict__ blocksum,
                                                       int n, int E) {
  int i = blockIdx.x * 256 + threadIdx.x;
  if (i < n) row_ptr[i] += blocksum[blockIdx.x];
  if (i == 0) row_ptr[n] = E;
}

__global__ void scatter_kernel(const int* __restrict__ ei, const float* __restrict__ ew,
                               const float* __restrict__ dinv, const int* __restrict__ row_ptr,
                               int* fill, int2* __restrict__ csr, int E) {
  int e = blockIdx.x * blockDim.x + threadIdx.x;
  if (e < E) {
    int src = ei[e];
    int dst = ei[E + e];
    int pos = row_ptr[dst] + atomicAdd(&fill[dst], 1);
    int2 p;
    p.x = src;
    p.y = __float_as_int(ew[e] * dinv[src]);
    csr[pos] = p;
  }
}

// ---------- SpMM layer0: fp32, 16ch, 16 lanes/node ----------
__global__ __launch_bounds__(256) void spmm16_kernel(
    const float* __restrict__ x, const float* __restrict__ dinv,
    const int* __restrict__ row_ptr, const int2* __restrict__ csr,
    float* __restrict__ A0, int n) {
  int lane = threadIdx.x & 15;
  int v = blockIdx.x * 16 + (threadIdx.x >> 4);
  if (v >= n) return;
  int beg = row_ptr[v], end = row_ptr[v + 1];
  float sum = 0.f;
  for (int e = beg; e < end; e += 4) {
#pragma unroll
    for (int i = 0; i < 4; ++i) {
      int ee = e + i;
      bool ok = ee < end;
      int2 p = csr[ok ? ee : beg];
      float w = ok ? __int_as_float(p.y) : 0.f;
      sum += w * x[(size_t)p.x * 16 + lane];
    }
  }
  float dv = dinv[v];
  float self = x[(size_t)v * 16 + lane];
  A0[(size_t)v * 16 + lane] = dv * sum + dv * dv * self;
}

// ---------- SpMM layers 1-3: bf16 packed, one wave per node ----------
__global__ __launch_bounds__(256) void spmm_bf16_kernel(
    const unsigned int* __restrict__ Hb, const float* __restrict__ dinv,
    const int* __restrict__ row_ptr, const int2* __restrict__ csr,
    unsigned int* __restrict__ Ab, int n) {
  int lane = threadIdx.x & 63;
  int v = (blockIdx.x << 2) + (threadIdx.x >> 6);
  if (v >= n) return;
  int beg = row_ptr[v], end = row_ptr[v + 1];
  float s0 = 0.f, s1 = 0.f;
  for (int e = beg; e < end; e += 4) {
#pragma unroll
    for (int i = 0; i < 4; ++i) {
      int ee = e + i;
      bool ok = ee < end;
      int2 p = csr[ok ? ee : beg];
      float w = ok ? __int_as_float(p.y) : 0.f;
      unsigned int g = Hb[((size_t)p.x << 6) + lane];
      s0 += w * bf16lo(g);
      s1 += w * bf16hi(g);
    }
  }
  float dv = dinv[v];
  unsigned int self = Hb[((size_t)v << 6) + lane];
  s0 = dv * s0 + dv * dv * bf16lo(self);
  s1 = dv * s1 + dv * dv * bf16hi(self);
  Ab[((size_t)v << 6) + lane] = bf16_rne(s0) | (bf16_rne(s1) << 16);
}

// ---------- GEMM layer0: fp32 X[n,16] @ W[16,128] + b, relu, bf16 out ----------
__global__ __launch_bounds__(256) void gemm16_kernel(
    const float* __restrict__ X, const float* __restrict__ W,
    const float* __restrict__ bias, unsigned int* __restrict__ Hb, int n) {
  __shared__ float Ws[16][128];
  __shared__ float Xs[32][16];
  const int tid = threadIdx.x;
  const int row0 = blockIdx.x * 32;

  for (int i = tid * 4; i < 16 * 128; i += 1024)
    *(float4*)&Ws[0][i] = *(const float4*)&W[i];
  for (int i = tid * 4; i < 32 * 16; i += 1024) {
    int r = i / 16, k = i % 16;
    int rr = row0 + r;
    float4 v = make_float4(0.f, 0.f, 0.f, 0.f);
    if (rr < n) v = *(const float4*)&X[(size_t)rr * 16 + k];
    *(float4*)&Xs[r][k] = v;
  }
  __syncthreads();

  const int tc = (tid & 31) * 4;
  const int tr = (tid >> 5) * 4;
  float acc[4][4] = {};
  for (int k = 0; k < 16; k += 4) {
    float4 xv[4];
#pragma unroll
    for (int r = 0; r < 4; ++r) xv[r] = *(const float4*)&Xs[tr + r][k];
    float4 wv[4];
#pragma unroll
    for (int kk = 0; kk < 4; ++kk) wv[kk] = *(const float4*)&Ws[k + kk][tc];
#pragma unroll
    for (int r = 0; r < 4; ++r) {
      float xr[4] = {xv[r].x, xv[r].y, xv[r].z, xv[r].w};
#pragma unroll
      for (int kk = 0; kk < 4; ++kk) {
        acc[r][0] += xr[kk] * wv[kk].x;
        acc[r][1] += xr[kk] * wv[kk].y;
        acc[r][2] += xr[kk] * wv[kk].z;
        acc[r][3] += xr[kk] * wv[kk].w;
      }
    }
  }

  float4 bv = *(const float4*)&bias[tc];
#pragma unroll
  for (int r = 0; r < 4; ++r) {
    int rr = row0 + tr + r;
    if (rr < n) {
      float o0 = fmaxf(acc[r][0] + bv.x, 0.f);
      float o1 = fmaxf(acc[r][1] + bv.y, 0.f);
      float o2 = fmaxf(acc[r][2] + bv.z, 0.f);
      float o3 = fmaxf(acc[r][3] + bv.w, 0.f);
      uint2 st;
      st.x = bf16_rne(o0) | (bf16_rne(o1) << 16);
      st.y = bf16_rne(o2) | (bf16_rne(o3) << 16);
      *(uint2*)&Hb[(size_t)rr * 64 + (tc >> 1)] = st;
    }
  }
}

// ---------- weight prep: fp32 W[k][c] -> packed bf16 Wt[c][kpair] ----------
__global__ void prep_wt_kernel(const float* __restrict__ W, unsigned int* __restrict__ Wt) {
  int idx = blockIdx.x * 256 + threadIdx.x;
  if (idx >= 128 * 64) return;
  int c = idx >> 6, kp = idx & 63;
  float f0 = W[(2 * kp) * 128 + c];
  float f1 = W[(2 * kp + 1) * 128 + c];
  Wt[idx] = bf16_rne(f0) | (bf16_rne(f1) << 16);
}

// ---------- MFMA GEMM: bf16 A[n,128] @ W[128,128] + b, relu, bf16 out ----------
__global__ __launch_bounds__(256) void gemm_mfma_kernel(
    const unsigned int* __restrict__ Ab, const unsigned int* __restrict__ Wtb,
    const float* __restrict__ bias, unsigned short* __restrict__ Hh, int n) {
  __shared__ unsigned int Wlds[128 * 68];  // row stride 68 uints = 272B (16B pad)
  const int tid = threadIdx.x;
  for (int idx = tid; idx < 128 * 16; idx += 256) {
    int row = idx >> 4, slot = idx & 15;
    uint4 v = ((const uint4*)Wtb)[idx];
    *(uint4*)&Wlds[row * 68 + slot * 4] = v;
  }
  __syncthreads();

  const int lane = tid & 63, wid = tid >> 6;
  const int r0 = blockIdx.x * 128 + wid * 32;
  const int rowA = r0 + (lane & 15);
  const int kgrp = lane >> 4;
  const uint4* Abase = (const uint4*)Ab;

  f32x4 acc[2][8] = {};
#pragma unroll
  for (int kstep = 0; kstep < 4; ++kstep) {
    short8 a[2];
#pragma unroll
    for (int rb = 0; rb < 2; ++rb)
      a[rb] = as_short8(Abase[(size_t)(rowA + rb * 16) * 16 + kstep * 4 + kgrp]);
#pragma unroll
    for (int cb = 0; cb < 8; ++cb) {
      short8 b = as_short8(*(const uint4*)&Wlds[(cb * 16 + (lane & 15)) * 68 + (kstep * 4 + kgrp) * 4]);
      acc[0][cb] = __builtin_amdgcn_mfma_f32_16x16x32_bf16(a[0], b, acc[0][cb], 0, 0, 0);
      acc[1][cb] = __builtin_amdgcn_mfma_f32_16x16x32_bf16(a[1], b, acc[1][cb], 0, 0, 0);
    }
  }

  const int rbase = kgrp * 4;
#pragma unroll
  for (int cb = 0; cb < 8; ++cb) {
    int col = cb * 16 + (lane & 15);
    float bv = bias[col];
#pragma unroll
    for (int rb = 0; rb < 2; ++rb) {
#pragma unroll
      for (int i = 0; i < 4; ++i) {
        int row = r0 + rb * 16 + rbase + i;
        if (row < n) {
          float o = fmaxf(acc[rb][cb][i] + bv, 0.f);
          Hh[(size_t)row * 128 + col] = (unsigned short)bf16_rne(o);
        }
      }
    }
  }
}

// ---------- mean pool (bf16 in, fp32 out) ----------
__global__ __launch_bounds__(256) void pool_kernel(
    const unsigned int* __restrict__ Hb, const int* __restrict__ batch,
    float* __restrict__ gp, int n) {
  int g = blockIdx.x;
  int lo = 0, hi = n;
  while (lo < hi) { int mid = (lo + hi) >> 1; if (batch[mid] < g) lo = mid + 1; else hi = mid; }
  int start = lo;
  lo = start; hi = n;
  while (lo < hi) { int mid = (lo + hi) >> 1; if (batch[mid] < g + 1) lo = mid + 1; else hi = mid; }
  int end = lo;

  int lane = threadIdx.x & 63, grp = threadIdx.x >> 6;
  float s0 = 0.f, s1 = 0.f;
  for (int v = start + grp; v < end; v += 4) {
    unsigned int u = Hb[((size_t)v << 6) + lane];
    s0 += bf16lo(u);
    s1 += bf16hi(u);
  }
  __shared__ float red[4][128];
  red[grp][2 * lane] = s0;
  red[grp][2 * lane + 1] = s1;
  __syncthreads();
  if (threadIdx.x < 128) {
    float t = red[0][threadIdx.x] + red[1][threadIdx.x] + red[2][threadIdx.x] + red[3][threadIdx.x];
    float cnt = (float)(end - start);
    gp[g * 128 + threadIdx.x] = t / fmaxf(cnt, 1.0f);
  }
}

// ---------- context MLP ----------
__global__ __launch_bounds__(128) void ctx_kernel(
    const float* __restrict__ xc,
    const float* __restrict__ W0, const float* __restrict__ b0,
    const float* __restrict__ W1, const float* __restrict__ b1,
    const float* __restrict__ W2, const float* __restrict__ b2,
    float* __restrict__ out) {
  int g = blockIdx.x, c = threadIdx.x;
  __shared__ float buf[128];
  __shared__ float xin[16];
  if (c < 16) xin[c] = xc[g * 16 + c];
  __syncthreads();
  float a = b0[c];
#pragma unroll
  for (int k = 0; k < 16; ++k) a += xin[k] * W0[k * 128 + c];
  a = fmaxf(a, 0.f);
  buf[c] = a;
  __syncthreads();
  float a1 = b1[c];
  for (int k = 0; k < 128; ++k) a1 += buf[k] * W1[k * 128 + c];
  a1 = fmaxf(a1, 0.f);
  __syncthreads();
  buf[c] = a1;
  __syncthreads();
  float a2 = b2[c];
  for (int k = 0; k < 128; ++k) a2 += buf[k] * W2[k * 128 + c];
  a2 = fmaxf(a2, 0.f);
  out[g * 128 + c] = a2;
}

// ---------- head ----------
__global__ __launch_bounds__(128) void head_kernel(
    const float* __restrict__ gp, const float* __restrict__ ctx,
    const float* __restrict__ W0, const float* __restrict__ b0,
    const float* __restrict__ W1, const float* __restrict__ b1,
    const float* __restrict__ W2, const float* __restrict__ b2,
    float* __restrict__ out) {
  int g = blockIdx.x, c = threadIdx.x;
  __shared__ float z[256];
  __shared__ float buf[128];
  z[c] = gp[g * 128 + c];
  z[128 + c] = ctx[g * 128 + c];
  __syncthreads();
  float a = b0[c];
  for (int k = 0; k < 256; ++k) a += z[k] * W0[k * 128 + c];
  a = fmaxf(a, 0.f);
  buf[c] = a;
  __syncthreads();
  float a1 = b1[c];
  for (int k = 0; k < 128; ++k) a1 += buf[k] * W1[k * 128 + c];
  a1 = fmaxf(a1, 0.f);
  __syncthreads();
  buf[c] = a1;
  __syncthreads();
  float a2 = b2[c];
  for (int k = 0; k < 128; ++k) a2 += buf[k] * W2[k * 128 + c];
  out[g * 128 + c] = a2;
}

// ---------- launch ----------
extern "C" void kernel_launch(void* const* d_in, const int* in_sizes, int n_in,
                              void* d_out, int out_size, void* d_ws, size_t ws_size,
                              hipStream_t stream) {
  const float* x     = (const float*)d_in[0];
  const float* xc    = (const float*)d_in[1];
  const int*   ei    = (const int*)d_in[2];
  const int*   batch = (const int*)d_in[3];
  const float* ew    = (const float*)d_in[4];
  const float* gW[4] = {(const float*)d_in[5], (const float*)d_in[7], (const float*)d_in[9],  (const float*)d_in[11]};
  const float* gb[4] = {(const float*)d_in[6], (const float*)d_in[8], (const float*)d_in[10], (const float*)d_in[12]};
  const float* cW0 = (const float*)d_in[13]; const float* cb0 = (const float*)d_in[14];
  const float* cW1 = (const float*)d_in[15]; const float* cb1 = (const float*)d_in[16];
  const float* cW2 = (const float*)d_in[17]; const float* cb2 = (const float*)d_in[18];
  const float* fW0 = (const float*)d_in[19]; const float* fb0 = (const float*)d_in[20];
  const float* fW1 = (const float*)d_in[21]; const float* fb1 = (const float*)d_in[22];
  const float* fW2 = (const float*)d_in[23]; const float* fb2 = (const float*)d_in[24];
  float* out = (float*)d_out;

  const int N = in_sizes[3];
  const int E = in_sizes[4];
  const int G = in_sizes[1] / IN_CH;
  const int Np = (N + 127) & ~127;

  char* p = (char*)d_ws;
  auto alloc = [&](size_t bytes) { char* r = p; p += (bytes + 255) & ~(size_t)255; return r; };
  float* deg      = (float*)alloc((size_t)N * 4);
  float* dinv     = (float*)alloc((size_t)N * 4);
  int*   cnt      = (int*)  alloc((size_t)N * 4);
  int*   fill     = (int*)  alloc((size_t)N * 4);
  int*   row_ptr  = (int*)  alloc((size_t)(N + 1) * 4);
  int*   blocksum = (int*)  alloc((size_t)256 * 4);
  int2*  csr      = (int2*) alloc((size_t)E * 8);
  float* A0       = (float*)alloc((size_t)N * 16 * 4);
  unsigned int* Ab = (unsigned int*)alloc((size_t)Np * 64 * 4);
  unsigned int* Hb = (unsigned int*)alloc((size_t)Np * 64 * 4);
  unsigned int* Wt[3];
  for (int l = 0; l < 3; ++l) Wt[l] = (unsigned int*)alloc((size_t)128 * 64 * 4);
  float* gp   = (float*)alloc((size_t)G * 128 * 4);
  float* cbuf = (float*)alloc((size_t)G * 128 * 4);

  int nbN = (N + 255) / 256;
  int nbE = (E + 255) / 256;
  int nbS = (N + 255) / 256;

  // CSR build
  init_kernel<<<nbN, 256, 0, stream>>>(deg, cnt, fill, N);
  count_kernel<<<nbE, 256, 0, stream>>>(ei, ew, deg, cnt, E);
  dinv_kernel<<<nbN, 256, 0, stream>>>(deg, dinv, N);
  scan_block_kernel<<<nbS, 256, 0, stream>>>(cnt, row_ptr, blocksum, N);
  scan_top_kernel<<<1, 256, 0, stream>>>(blocksum, nbS);
  scan_add_kernel<<<nbS, 256, 0, stream>>>(row_ptr, blocksum, N, E);
  scatter_kernel<<<nbE, 256, 0, stream>>>(ei, ew, dinv, row_ptr, fill, csr, E);

  // weight prep (layers 1-3)
  for (int l = 0; l < 3; ++l)
    prep_wt_kernel<<<32, 256, 0, stream>>>(gW[l + 1], Wt[l]);

  // layer 0
  spmm16_kernel<<<(N + 15) / 16, 256, 0, stream>>>(x, dinv, row_ptr, csr, A0, N);
  gemm16_kernel<<<(N + 31) / 32, 256, 0, stream>>>(A0, gW[0], gb[0], Hb, N);

  // layers 1-3
  for (int l = 0; l < 3; ++l) {
    spmm_bf16_kernel<<<(N + 3) / 4, 256, 0, stream>>>(Hb, dinv, row_ptr, csr, Ab, N);
    gemm_mfma_kernel<<<Np / 128, 256, 0, stream>>>(Ab, Wt[l], gb[l + 1], (unsigned short*)Hb, N);
  }

  // pool + context + head
  pool_kernel<<<G, 256, 0, stream>>>(Hb, batch, gp, N);
  ctx_kernel<<<G, 128, 0, stream>>>(xc, cW0, cb0, cW1, cb1, cW2, cb2, cbuf);
  head_kernel<<<G, 128, 0, stream>>>(gp, cbuf, fW0, fb0, fW1, fb1, fW2, fb2, out);
}

// Round 3
// 466.179 us; speedup vs baseline: 2.0130x; 1.0028x over previous
//
#include <hip/hip_runtime.h>

typedef __attribute__((ext_vector_type(8))) short short8;
typedef __attribute__((ext_vector_type(4))) float f32x4;

#define IN_CH 16
#define NREP 8

// ---------- helpers ----------
__device__ inline unsigned int bf16_rne(float f) {
  unsigned int u = __float_as_uint(f);
  unsigned int r = u + 0x7fffu + ((u >> 16) & 1u);
  return r >> 16;
}
__device__ inline float bf16lo(unsigned int g) { return __uint_as_float(g << 16); }
__device__ inline float bf16hi(unsigned int g) { return __uint_as_float(g & 0xffff0000u); }
__device__ inline short8 as_short8(uint4 u) {
  union { uint4 u; short8 s; } cv; cv.u = u; return cv.s;
}

// ---------- zero workspace counters ----------
__global__ void zero_kernel(int* __restrict__ cnt_r, float* __restrict__ deg_r,
                            int* __restrict__ fill, int n) {
  int i = blockIdx.x * blockDim.x + threadIdx.x;
  int total = NREP * n;
  for (int j = i; j < total; j += gridDim.x * blockDim.x) {
    cnt_r[j] = 0;
    deg_r[j] = 0.f;
  }
  for (int j = i; j < n; j += gridDim.x * blockDim.x) fill[j] = 0;
}

// ---------- count with 8-way replication ----------
__global__ void count_kernel(const int* __restrict__ ei, const float* __restrict__ ew,
                             float* __restrict__ deg_r, int* __restrict__ cnt_r,
                             int n, int E) {
  int e = blockIdx.x * blockDim.x + threadIdx.x;
  int rep = blockIdx.x & (NREP - 1);
  if (e < E) {
    int dst = ei[E + e];
    atomicAdd(&deg_r[rep * n + dst], ew[e]);
    atomicAdd(&cnt_r[rep * n + dst], 1);
  }
}

// ---------- reduce replicas -> cnt, dinv ----------
__global__ void reduce_kernel(const int* __restrict__ cnt_r, const float* __restrict__ deg_r,
                              int* __restrict__ cnt, float* __restrict__ dinv, int n) {
  int i = blockIdx.x * blockDim.x + threadIdx.x;
  if (i >= n) return;
  int c = 0;
  float d = 1.0f;  // self loop weight
#pragma unroll
  for (int r = 0; r < NREP; ++r) {
    c += cnt_r[r * n + i];
    d += deg_r[r * n + i];
  }
  cnt[i] = c;
  dinv[i] = (d > 0.f) ? rsqrtf(d) : 0.f;
}

// ---------- hierarchical exclusive scan ----------
__global__ __launch_bounds__(256) void scan_block_kernel(const int* __restrict__ cnt,
                                                         int* __restrict__ row_ptr,
                                                         int* __restrict__ blocksum, int n) {
  int i = blockIdx.x * 256 + threadIdx.x;
  int v = (i < n) ? cnt[i] : 0;
  int lane = threadIdx.x & 63;
  int incl = v;
#pragma unroll
  for (int off = 1; off < 64; off <<= 1) {
    int t = __shfl_up(incl, off);
    if (lane >= off) incl += t;
  }
  __shared__ int wsum[4];
  int w = threadIdx.x >> 6;
  if (lane == 63) wsum[w] = incl;
  __syncthreads();
  if (threadIdx.x == 0) {
    int a = wsum[0], b = wsum[1], c = wsum[2], d = wsum[3];
    wsum[0] = 0; wsum[1] = a; wsum[2] = a + b; wsum[3] = a + b + c;
    blocksum[blockIdx.x] = a + b + c + d;
  }
  __syncthreads();
  int excl = incl - v + wsum[w];
  if (i < n) row_ptr[i] = excl;
}

__global__ __launch_bounds__(256) void scan_top_kernel(int* __restrict__ blocksum, int nb) {
  int v = (threadIdx.x < nb) ? blocksum[threadIdx.x] : 0;
  int lane = threadIdx.x & 63;
  int incl = v;
#pragma unroll
  for (int off = 1; off < 64; off <<= 1) {
    int t = __shfl_up(incl, off);
    if (lane >= off) incl += t;
  }
  __shared__ int wsum[4];
  int w = threadIdx.x >> 6;
  if (lane == 63) wsum[w] = incl;
  __syncthreads();
  if (threadIdx.x == 0) {
    int a = wsum[0], b = wsum[1], c = wsum[2];
    wsum[3] = a + b + c; wsum[2] = a + b; wsum[1] = a; wsum[0] = 0;
  }
  __syncthreads();
  int excl = incl - v + wsum[w];
  if (threadIdx.x < nb) blocksum[threadIdx.x] = excl;
}

__global__ __launch_bounds__(256) void scan_add_kernel(int* __restrict__ row_ptr,
                                                       const int* __restrict__ blocksum,
                                                       int n, int E) {
  int i = blockIdx.x * 256 + threadIdx.x;
  if (i < n) row_ptr[i] += blocksum[blockIdx.x];
  if (i == 0) row_ptr[n] = E;
}

__global__ void scatter_kernel(const int* __restrict__ ei, const float* __restrict__ ew,
                               const float* __restrict__ dinv, const int* __restrict__ row_ptr,
                               int* fill, int2* __restrict__ csr, int E) {
  int e = blockIdx.x * blockDim.x + threadIdx.x;
  if (e < E) {
    int src = ei[e];
    int dst = ei[E + e];
    int pos = row_ptr[dst] + atomicAdd(&fill[dst], 1);
    int2 p;
    p.x = src;
    p.y = __float_as_int(ew[e] * dinv[src]);
    csr[pos] = p;
  }
}

// ---------- SpMM layer0: fp32, 16ch, 16 lanes/node ----------
__global__ __launch_bounds__(256) void spmm16_kernel(
    const float* __restrict__ x, const float* __restrict__ dinv,
    const int* __restrict__ row_ptr, const int2* __restrict__ csr,
    float* __restrict__ A0, int n) {
  int lane = threadIdx.x & 15;
  int v = blockIdx.x * 16 + (threadIdx.x >> 4);
  if (v >= n) return;
  int beg = row_ptr[v], end = row_ptr[v + 1];
  float sum = 0.f;
  for (int e = beg; e < end; e += 8) {
#pragma unroll
    for (int i = 0; i < 8; ++i) {
      int ee = e + i;
      bool ok = ee < end;
      int2 p = csr[ok ? ee : beg];
      float w = ok ? __int_as_float(p.y) : 0.f;
      sum += w * x[(size_t)p.x * 16 + lane];
    }
  }
  float dv = dinv[v];
  float self = x[(size_t)v * 16 + lane];
  A0[(size_t)v * 16 + lane] = dv * sum + dv * dv * self;
}

// ---------- SpMM layers 1-3: bf16 packed, one wave per node, 8 gathers in flight ----------
__global__ __launch_bounds__(256) void spmm_bf16_kernel(
    const unsigned int* __restrict__ Hb, const float* __restrict__ dinv,
    const int* __restrict__ row_ptr, const int2* __restrict__ csr,
    unsigned int* __restrict__ Ab, int n) {
  int lane = threadIdx.x & 63;
  int v = (blockIdx.x << 2) + (threadIdx.x >> 6);
  if (v >= n) return;
  int beg = row_ptr[v], end = row_ptr[v + 1];
  float s0 = 0.f, s1 = 0.f;
  for (int e = beg; e < end; e += 8) {
#pragma unroll
    for (int i = 0; i < 8; ++i) {
      int ee = e + i;
      bool ok = ee < end;
      int2 p = csr[ok ? ee : beg];
      float w = ok ? __int_as_float(p.y) : 0.f;
      unsigned int g = Hb[((size_t)p.x << 6) + lane];
      s0 += w * bf16lo(g);
      s1 += w * bf16hi(g);
    }
  }
  float dv = dinv[v];
  unsigned int self = Hb[((size_t)v << 6) + lane];
  s0 = dv * s0 + dv * dv * bf16lo(self);
  s1 = dv * s1 + dv * dv * bf16hi(self);
  Ab[((size_t)v << 6) + lane] = bf16_rne(s0) | (bf16_rne(s1) << 16);
}

// ---------- GEMM layer0: fp32 X[n,16] @ W[16,128] + b, relu, bf16 out ----------
__global__ __launch_bounds__(256) void gemm16_kernel(
    const float* __restrict__ X, const float* __restrict__ W,
    const float* __restrict__ bias, unsigned int* __restrict__ Hb, int n) {
  __shared__ float Ws[16][128];
  __shared__ float Xs[32][16];
  const int tid = threadIdx.x;
  const int row0 = blockIdx.x * 32;

  for (int i = tid * 4; i < 16 * 128; i += 1024)
    *(float4*)&Ws[0][i] = *(const float4*)&W[i];
  for (int i = tid * 4; i < 32 * 16; i += 1024) {
    int r = i / 16, k = i % 16;
    int rr = row0 + r;
    float4 v = make_float4(0.f, 0.f, 0.f, 0.f);
    if (rr < n) v = *(const float4*)&X[(size_t)rr * 16 + k];
    *(float4*)&Xs[r][k] = v;
  }
  __syncthreads();

  const int tc = (tid & 31) * 4;
  const int tr = (tid >> 5) * 4;
  float acc[4][4] = {};
  for (int k = 0; k < 16; k += 4) {
    float4 xv[4];
#pragma unroll
    for (int r = 0; r < 4; ++r) xv[r] = *(const float4*)&Xs[tr + r][k];
    float4 wv[4];
#pragma unroll
    for (int kk = 0; kk < 4; ++kk) wv[kk] = *(const float4*)&Ws[k + kk][tc];
#pragma unroll
    for (int r = 0; r < 4; ++r) {
      float xr[4] = {xv[r].x, xv[r].y, xv[r].z, xv[r].w};
#pragma unroll
      for (int kk = 0; kk < 4; ++kk) {
        acc[r][0] += xr[kk] * wv[kk].x;
        acc[r][1] += xr[kk] * wv[kk].y;
        acc[r][2] += xr[kk] * wv[kk].z;
        acc[r][3] += xr[kk] * wv[kk].w;
      }
    }
  }

  float4 bv = *(const float4*)&bias[tc];
#pragma unroll
  for (int r = 0; r < 4; ++r) {
    int rr = row0 + tr + r;
    if (rr < n) {
      float o0 = fmaxf(acc[r][0] + bv.x, 0.f);
      float o1 = fmaxf(acc[r][1] + bv.y, 0.f);
      float o2 = fmaxf(acc[r][2] + bv.z, 0.f);
      float o3 = fmaxf(acc[r][3] + bv.w, 0.f);
      uint2 st;
      st.x = bf16_rne(o0) | (bf16_rne(o1) << 16);
      st.y = bf16_rne(o2) | (bf16_rne(o3) << 16);
      *(uint2*)&Hb[(size_t)rr * 64 + (tc >> 1)] = st;
    }
  }
}

// ---------- weight prep: fp32 W[k][c] -> packed bf16 Wt[c][kpair] ----------
__global__ void prep_wt_kernel(const float* __restrict__ W, unsigned int* __restrict__ Wt) {
  int idx = blockIdx.x * 256 + threadIdx.x;
  if (idx >= 128 * 64) return;
  int c = idx >> 6, kp = idx & 63;
  float f0 = W[(2 * kp) * 128 + c];
  float f1 = W[(2 * kp + 1) * 128 + c];
  Wt[idx] = bf16_rne(f0) | (bf16_rne(f1) << 16);
}

// ---------- MFMA GEMM: bf16 A[n,128] @ W[128,128] + b, relu, bf16 out ----------
__global__ __launch_bounds__(256) void gemm_mfma_kernel(
    const unsigned int* __restrict__ Ab, const unsigned int* __restrict__ Wtb,
    const float* __restrict__ bias, unsigned short* __restrict__ Hh, int n) {
  __shared__ unsigned int Wlds[128 * 68];  // row stride 68 uints = 272B (16B pad)
  const int tid = threadIdx.x;
  for (int idx = tid; idx < 128 * 16; idx += 256) {
    int row = idx >> 4, slot = idx & 15;
    uint4 v = ((const uint4*)Wtb)[idx];
    *(uint4*)&Wlds[row * 68 + slot * 4] = v;
  }
  __syncthreads();

  const int lane = tid & 63, wid = tid >> 6;
  const int r0 = blockIdx.x * 128 + wid * 32;
  const int rowA = r0 + (lane & 15);
  const int kgrp = lane >> 4;
  const uint4* Abase = (const uint4*)Ab;

  f32x4 acc[2][8] = {};
#pragma unroll
  for (int kstep = 0; kstep < 4; ++kstep) {
    short8 a[2];
#pragma unroll
    for (int rb = 0; rb < 2; ++rb)
      a[rb] = as_short8(Abase[(size_t)(rowA + rb * 16) * 16 + kstep * 4 + kgrp]);
#pragma unroll
    for (int cb = 0; cb < 8; ++cb) {
      short8 b = as_short8(*(const uint4*)&Wlds[(cb * 16 + (lane & 15)) * 68 + (kstep * 4 + kgrp) * 4]);
      acc[0][cb] = __builtin_amdgcn_mfma_f32_16x16x32_bf16(a[0], b, acc[0][cb], 0, 0, 0);
      acc[1][cb] = __builtin_amdgcn_mfma_f32_16x16x32_bf16(a[1], b, acc[1][cb], 0, 0, 0);
    }
  }

  const int rbase = kgrp * 4;
#pragma unroll
  for (int cb = 0; cb < 8; ++cb) {
    int col = cb * 16 + (lane & 15);
    float bv = bias[col];
#pragma unroll
    for (int rb = 0; rb < 2; ++rb) {
#pragma unroll
      for (int i = 0; i < 4; ++i) {
        int row = r0 + rb * 16 + rbase + i;
        if (row < n) {
          float o = fmaxf(acc[rb][cb][i] + bv, 0.f);
          Hh[(size_t)row * 128 + col] = (unsigned short)bf16_rne(o);
        }
      }
    }
  }
}

// ---------- mean pool (bf16 in, fp32 out) ----------
__global__ __launch_bounds__(256) void pool_kernel(
    const unsigned int* __restrict__ Hb, const int* __restrict__ batch,
    float* __restrict__ gp, int n) {
  int g = blockIdx.x;
  int lo = 0, hi = n;
  while (lo < hi) { int mid = (lo + hi) >> 1; if (batch[mid] < g) lo = mid + 1; else hi = mid; }
  int start = lo;
  lo = start; hi = n;
  while (lo < hi) { int mid = (lo + hi) >> 1; if (batch[mid] < g + 1) lo = mid + 1; else hi = mid; }
  int end = lo;

  int lane = threadIdx.x & 63, grp = threadIdx.x >> 6;
  float s0 = 0.f, s1 = 0.f;
  for (int v = start + grp; v < end; v += 4) {
    unsigned int u = Hb[((size_t)v << 6) + lane];
    s0 += bf16lo(u);
    s1 += bf16hi(u);
  }
  __shared__ float red[4][128];
  red[grp][2 * lane] = s0;
  red[grp][2 * lane + 1] = s1;
  __syncthreads();
  if (threadIdx.x < 128) {
    float t = red[0][threadIdx.x] + red[1][threadIdx.x] + red[2][threadIdx.x] + red[3][threadIdx.x];
    float cnt = (float)(end - start);
    gp[g * 128 + threadIdx.x] = t / fmaxf(cnt, 1.0f);
  }
}

// ---------- context MLP + head fused (per-graph) ----------
__global__ __launch_bounds__(128) void ctx_head_kernel(
    const float* __restrict__ xc, const float* __restrict__ gp,
    const float* __restrict__ cW0, const float* __restrict__ cb0,
    const float* __restrict__ cW1, const float* __restrict__ cb1,
    const float* __restrict__ cW2, const float* __restrict__ cb2,
    const float* __restrict__ fW0, const float* __restrict__ fb0,
    const float* __restrict__ fW1, const float* __restrict__ fb1,
    const float* __restrict__ fW2, const float* __restrict__ fb2,
    float* __restrict__ out) {
  int g = blockIdx.x, c = threadIdx.x;
  __shared__ float xin[16];
  __shared__ float buf[128];
  __shared__ float z[256];

  if (c < 16) xin[c] = xc[g * 16 + c];
  __syncthreads();
  float a = cb0[c];
#pragma unroll
  for (int k = 0; k < 16; ++k) a += xin[k] * cW0[k * 128 + c];
  buf[c] = fmaxf(a, 0.f);
  __syncthreads();
  float a1 = cb1[c];
  for (int k = 0; k < 128; ++k) a1 += buf[k] * cW1[k * 128 + c];
  a1 = fmaxf(a1, 0.f);
  __syncthreads();
  buf[c] = a1;
  __syncthreads();
  float a2 = cb2[c];
  for (int k = 0; k < 128; ++k) a2 += buf[k] * cW2[k * 128 + c];
  a2 = fmaxf(a2, 0.f);

  // concat [gp, ctx]
  z[c] = gp[g * 128 + c];
  z[128 + c] = a2;
  __syncthreads();
  float h0 = fb0[c];
  for (int k = 0; k < 256; ++k) h0 += z[k] * fW0[k * 128 + c];
  h0 = fmaxf(h0, 0.f);
  __syncthreads();
  buf[c] = h0;
  __syncthreads();
  float h1 = fb1[c];
  for (int k = 0; k < 128; ++k) h1 += buf[k] * fW1[k * 128 + c];
  h1 = fmaxf(h1, 0.f);
  __syncthreads();
  buf[c] = h1;
  __syncthreads();
  float h2 = fb2[c];
  for (int k = 0; k < 128; ++k) h2 += buf[k] * fW2[k * 128 + c];
  out[g * 128 + c] = h2;
}

// ---------- launch ----------
extern "C" void kernel_launch(void* const* d_in, const int* in_sizes, int n_in,
                              void* d_out, int out_size, void* d_ws, size_t ws_size,
                              hipStream_t stream) {
  const float* x     = (const float*)d_in[0];
  const float* xc    = (const float*)d_in[1];
  const int*   ei    = (const int*)d_in[2];
  const int*   batch = (const int*)d_in[3];
  const float* ew    = (const float*)d_in[4];
  const float* gW[4] = {(const float*)d_in[5], (const float*)d_in[7], (const float*)d_in[9],  (const float*)d_in[11]};
  const float* gb[4] = {(const float*)d_in[6], (const float*)d_in[8], (const float*)d_in[10], (const float*)d_in[12]};
  const float* cW0 = (const float*)d_in[13]; const float* cb0 = (const float*)d_in[14];
  const float* cW1 = (const float*)d_in[15]; const float* cb1 = (const float*)d_in[16];
  const float* cW2 = (const float*)d_in[17]; const float* cb2 = (const float*)d_in[18];
  const float* fW0 = (const float*)d_in[19]; const float* fb0 = (const float*)d_in[20];
  const float* fW1 = (const float*)d_in[21]; const float* fb1 = (const float*)d_in[22];
  const float* fW2 = (const float*)d_in[23]; const float* fb2 = (const float*)d_in[24];
  float* out = (float*)d_out;

  const int N = in_sizes[3];
  const int E = in_sizes[4];
  const int G = in_sizes[1] / IN_CH;
  const int Np = (N + 127) & ~127;

  char* p = (char*)d_ws;
  auto alloc = [&](size_t bytes) { char* r = p; p += (bytes + 255) & ~(size_t)255; return r; };
  int*   cnt_r    = (int*)  alloc((size_t)NREP * N * 4);
  float* deg_r    = (float*)alloc((size_t)NREP * N * 4);
  float* dinv     = (float*)alloc((size_t)N * 4);
  int*   cnt      = (int*)  alloc((size_t)N * 4);
  int*   fill     = (int*)  alloc((size_t)N * 4);
  int*   row_ptr  = (int*)  alloc((size_t)(N + 1) * 4);
  int*   blocksum = (int*)  alloc((size_t)256 * 4);
  int2*  csr      = (int2*) alloc((size_t)E * 8);
  float* A0       = (float*)alloc((size_t)N * 16 * 4);
  unsigned int* Ab = (unsigned int*)alloc((size_t)Np * 64 * 4);
  unsigned int* Hb = (unsigned int*)alloc((size_t)Np * 64 * 4);
  unsigned int* Wt[3];
  for (int l = 0; l < 3; ++l) Wt[l] = (unsigned int*)alloc((size_t)128 * 64 * 4);
  float* gp   = (float*)alloc((size_t)G * 128 * 4);

  int nbN = (N + 255) / 256;
  int nbE = (E + 255) / 256;
  int nbS = (N + 255) / 256;

  // CSR build
  zero_kernel<<<512, 256, 0, stream>>>(cnt_r, deg_r, fill, N);
  count_kernel<<<nbE, 256, 0, stream>>>(ei, ew, deg_r, cnt_r, N, E);
  reduce_kernel<<<nbN, 256, 0, stream>>>(cnt_r, deg_r, cnt, dinv, N);
  scan_block_kernel<<<nbS, 256, 0, stream>>>(cnt, row_ptr, blocksum, N);
  scan_top_kernel<<<1, 256, 0, stream>>>(blocksum, nbS);
  scan_add_kernel<<<nbS, 256, 0, stream>>>(row_ptr, blocksum, N, E);
  scatter_kernel<<<nbE, 256, 0, stream>>>(ei, ew, dinv, row_ptr, fill, csr, E);

  // weight prep (layers 1-3)
  for (int l = 0; l < 3; ++l)
    prep_wt_kernel<<<32, 256, 0, stream>>>(gW[l + 1], Wt[l]);

  // layer 0
  spmm16_kernel<<<(N + 15) / 16, 256, 0, stream>>>(x, dinv, row_ptr, csr, A0, N);
  gemm16_kernel<<<(N + 31) / 32, 256, 0, stream>>>(A0, gW[0], gb[0], Hb, N);

  // layers 1-3
  for (int l = 0; l < 3; ++l) {
    spmm_bf16_kernel<<<(N + 3) / 4, 256, 0, stream>>>(Hb, dinv, row_ptr, csr, Ab, N);
    gemm_mfma_kernel<<<Np / 128, 256, 0, stream>>>(Ab, Wt[l], gb[l + 1], (unsigned short*)Hb, N);
  }

  // pool + context/head
  pool_kernel<<<G, 256, 0, stream>>>(Hb, batch, gp, N);
  ctx_head_kernel<<<G, 128, 0, stream>>>(xc, gp, cW0, cb0, cW1, cb1, cW2, cb2,
                                         fW0, fb0, fW1, fb1, fW2, fb2, out);
}

// Round 5
// 404.584 us; speedup vs baseline: 2.3194x; 1.1522x over previous
//
#include <hip/hip_runtime.h>

typedef __attribute__((ext_vector_type(8))) short short8;
typedef __attribute__((ext_vector_type(4))) float f32x4;

#define IN_CH 16
#define DEG_SCALE 1048576.0f           // 2^20 fixed point for weighted degree
#define DEG_MASK ((1ULL << 40) - 1)

// ---------- helpers ----------
__device__ inline unsigned int bf16_rne(float f) {
  unsigned int u = __float_as_uint(f);
  unsigned int r = u + 0x7fffu + ((u >> 16) & 1u);
  return r >> 16;
}
__device__ inline float bf16lo(unsigned int g) { return __uint_as_float(g << 16); }
__device__ inline float bf16hi(unsigned int g) { return __uint_as_float(g & 0xffff0000u); }
__device__ inline short8 as_short8(uint4 u) {
  union { uint4 u; short8 s; } cv; cv.u = u; return cv.s;
}

// ---------- zero packed counters ----------
__global__ void zero_kernel(unsigned long long* __restrict__ packed, int n) {
  int i = blockIdx.x * blockDim.x + threadIdx.x;
  for (int j = i; j < n; j += gridDim.x * blockDim.x) packed[j] = 0ULL;
}

// ---------- count: ONE 64-bit atomic per edge; return value gives slot ----------
__global__ void count_kernel(const int* __restrict__ ei, const float* __restrict__ ew,
                             unsigned long long* __restrict__ packed,
                             unsigned int* __restrict__ slot, int E) {
  int e = blockIdx.x * blockDim.x + threadIdx.x;
  if (e < E) {
    int dst = ei[E + e];
    unsigned long long inc =
        (1ULL << 40) | (unsigned long long)(unsigned int)(ew[e] * DEG_SCALE);
    unsigned long long old = atomicAdd(&packed[dst], inc);
    slot[e] = (unsigned int)(old >> 40);
  }
}

// ---------- scan (block stage): unpack counts, emit dinv, partial exclusive scan ----------
__global__ __launch_bounds__(256) void scan_block_kernel(
    const unsigned long long* __restrict__ packed,
    int* __restrict__ row_ptr, int* __restrict__ blocksum,
    float* __restrict__ dinv, int n) {
  int i = blockIdx.x * 256 + threadIdx.x;
  int v = 0;
  if (i < n) {
    unsigned long long pk = packed[i];
    v = (int)(pk >> 40);
    float d = 1.0f + (float)(pk & DEG_MASK) * (1.0f / DEG_SCALE);  // self loop + edge sum
    dinv[i] = rsqrtf(d);
  }
  int lane = threadIdx.x & 63;
  int incl = v;
#pragma unroll
  for (int off = 1; off < 64; off <<= 1) {
    int t = __shfl_up(incl, off);
    if (lane >= off) incl += t;
  }
  __shared__ int wsum[4];
  int w = threadIdx.x >> 6;
  if (lane == 63) wsum[w] = incl;
  __syncthreads();
  if (threadIdx.x == 0) {
    int a = wsum[0], b = wsum[1], c = wsum[2], d = wsum[3];
    wsum[0] = 0; wsum[1] = a; wsum[2] = a + b; wsum[3] = a + b + c;
    blocksum[blockIdx.x] = a + b + c + d;
  }
  __syncthreads();
  int excl = incl - v + wsum[w];
  if (i < n) row_ptr[i] = excl;
}

__global__ __launch_bounds__(256) void scan_top_kernel(int* __restrict__ blocksum, int nb) {
  int v = (threadIdx.x < nb) ? blocksum[threadIdx.x] : 0;
  int lane = threadIdx.x & 63;
  int incl = v;
#pragma unroll
  for (int off = 1; off < 64; off <<= 1) {
    int t = __shfl_up(incl, off);
    if (lane >= off) incl += t;
  }
  __shared__ int wsum[4];
  int w = threadIdx.x >> 6;
  if (lane == 63) wsum[w] = incl;
  __syncthreads();
  if (threadIdx.x == 0) {
    int a = wsum[0], b = wsum[1], c = wsum[2];
    wsum[3] = a + b + c; wsum[2] = a + b; wsum[1] = a; wsum[0] = 0;
  }
  __syncthreads();
  int excl = incl - v + wsum[w];
  if (threadIdx.x < nb) blocksum[threadIdx.x] = excl;
}

__global__ __launch_bounds__(256) void scan_add_kernel(int* __restrict__ row_ptr,
                                                       const int* __restrict__ blocksum,
                                                       int n, int E) {
  int i = blockIdx.x * 256 + threadIdx.x;
  if (i < n) row_ptr[i] += blocksum[blockIdx.x];
  if (i == 0) row_ptr[n] = E;
}

// ---------- scatter: NO atomics (slot precomputed) ----------
__global__ void scatter_kernel(const int* __restrict__ ei, const float* __restrict__ ew,
                               const float* __restrict__ dinv, const int* __restrict__ row_ptr,
                               const unsigned int* __restrict__ slot,
                               int2* __restrict__ csr, int E) {
  int e = blockIdx.x * blockDim.x + threadIdx.x;
  if (e < E) {
    int src = ei[e];
    int dst = ei[E + e];
    int pos = row_ptr[dst] + (int)slot[e];
    int2 p;
    p.x = src;
    p.y = __float_as_int(ew[e] * dinv[src]);
    csr[pos] = p;
  }
}

// ---------- SpMM layer0: fp32, 16ch, 16 lanes/node ----------
__global__ __launch_bounds__(256) void spmm16_kernel(
    const float* __restrict__ x, const float* __restrict__ dinv,
    const int* __restrict__ row_ptr, const int2* __restrict__ csr,
    float* __restrict__ A0, int n) {
  int lane = threadIdx.x & 15;
  int v = blockIdx.x * 16 + (threadIdx.x >> 4);
  if (v >= n) return;
  int beg = row_ptr[v], end = row_ptr[v + 1];
  float sum = 0.f;
  for (int e = beg; e < end; e += 8) {
#pragma unroll
    for (int i = 0; i < 8; ++i) {
      int ee = e + i;
      bool ok = ee < end;
      int2 p = csr[ok ? ee : beg];
      float w = ok ? __int_as_float(p.y) : 0.f;
      sum += w * x[(size_t)p.x * 16 + lane];
    }
  }
  float dv = dinv[v];
  float self = x[(size_t)v * 16 + lane];
  A0[(size_t)v * 16 + lane] = dv * sum + dv * dv * self;
}

// ---------- SpMM layers 1-3: bf16 packed, one wave per node ----------
__global__ __launch_bounds__(256) void spmm_bf16_kernel(
    const unsigned int* __restrict__ Hb, const float* __restrict__ dinv,
    const int* __restrict__ row_ptr, const int2* __restrict__ csr,
    unsigned int* __restrict__ Ab, int n) {
  int lane = threadIdx.x & 63;
  int v = (blockIdx.x << 2) + (threadIdx.x >> 6);
  if (v >= n) return;
  int beg = row_ptr[v], end = row_ptr[v + 1];
  float s0 = 0.f, s1 = 0.f;
  for (int e = beg; e < end; e += 8) {
#pragma unroll
    for (int i = 0; i < 8; ++i) {
      int ee = e + i;
      bool ok = ee < end;
      int2 p = csr[ok ? ee : beg];
      float w = ok ? __int_as_float(p.y) : 0.f;
      unsigned int g = Hb[((size_t)p.x << 6) + lane];
      s0 += w * bf16lo(g);
      s1 += w * bf16hi(g);
    }
  }
  float dv = dinv[v];
  unsigned int self = Hb[((size_t)v << 6) + lane];
  s0 = dv * s0 + dv * dv * bf16lo(self);
  s1 = dv * s1 + dv * dv * bf16hi(self);
  Ab[((size_t)v << 6) + lane] = bf16_rne(s0) | (bf16_rne(s1) << 16);
}

// ---------- GEMM layer0: fp32 X[n,16] @ W[16,128] + b, relu, bf16 out ----------
__global__ __launch_bounds__(256) void gemm16_kernel(
    const float* __restrict__ X, const float* __restrict__ W,
    const float* __restrict__ bias, unsigned int* __restrict__ Hb, int n) {
  __shared__ float Ws[16][128];
  __shared__ float Xs[32][16];
  const int tid = threadIdx.x;
  const int row0 = blockIdx.x * 32;

  for (int i = tid * 4; i < 16 * 128; i += 1024)
    *(float4*)&Ws[0][i] = *(const float4*)&W[i];
  for (int i = tid * 4; i < 32 * 16; i += 1024) {
    int r = i / 16, k = i % 16;
    int rr = row0 + r;
    float4 v = make_float4(0.f, 0.f, 0.f, 0.f);
    if (rr < n) v = *(const float4*)&X[(size_t)rr * 16 + k];
    *(float4*)&Xs[r][k] = v;
  }
  __syncthreads();

  const int tc = (tid & 31) * 4;
  const int tr = (tid >> 5) * 4;
  float acc[4][4] = {};
  for (int k = 0; k < 16; k += 4) {
    float4 xv[4];
#pragma unroll
    for (int r = 0; r < 4; ++r) xv[r] = *(const float4*)&Xs[tr + r][k];
    float4 wv[4];
#pragma unroll
    for (int kk = 0; kk < 4; ++kk) wv[kk] = *(const float4*)&Ws[k + kk][tc];
#pragma unroll
    for (int r = 0; r < 4; ++r) {
      float xr[4] = {xv[r].x, xv[r].y, xv[r].z, xv[r].w};
#pragma unroll
      for (int kk = 0; kk < 4; ++kk) {
        acc[r][0] += xr[kk] * wv[kk].x;
        acc[r][1] += xr[kk] * wv[kk].y;
        acc[r][2] += xr[kk] * wv[kk].z;
        acc[r][3] += xr[kk] * wv[kk].w;
      }
    }
  }

  float4 bv = *(const float4*)&bias[tc];
#pragma unroll
  for (int r = 0; r < 4; ++r) {
    int rr = row0 + tr + r;
    if (rr < n) {
      float o0 = fmaxf(acc[r][0] + bv.x, 0.f);
      float o1 = fmaxf(acc[r][1] + bv.y, 0.f);
      float o2 = fmaxf(acc[r][2] + bv.z, 0.f);
      float o3 = fmaxf(acc[r][3] + bv.w, 0.f);
      uint2 st;
      st.x = bf16_rne(o0) | (bf16_rne(o1) << 16);
      st.y = bf16_rne(o2) | (bf16_rne(o3) << 16);
      *(uint2*)&Hb[(size_t)rr * 64 + (tc >> 1)] = st;
    }
  }
}

// ---------- weight prep: fp32 W[k][c] -> packed bf16 Wt[c][kpair] ----------
__global__ void prep_wt_kernel(const float* __restrict__ W, unsigned int* __restrict__ Wt) {
  int idx = blockIdx.x * 256 + threadIdx.x;
  if (idx >= 128 * 64) return;
  int c = idx >> 6, kp = idx & 63;
  float f0 = W[(2 * kp) * 128 + c];
  float f1 = W[(2 * kp + 1) * 128 + c];
  Wt[idx] = bf16_rne(f0) | (bf16_rne(f1) << 16);
}

// ---------- MFMA GEMM: bf16 A[n,128] @ W[128,128] + b, relu, bf16 out ----------
__global__ __launch_bounds__(256) void gemm_mfma_kernel(
    const unsigned int* __restrict__ Ab, const unsigned int* __restrict__ Wtb,
    const float* __restrict__ bias, unsigned short* __restrict__ Hh, int n) {
  __shared__ unsigned int Wlds[128 * 68];  // row stride 68 uints = 272B (16B pad)
  const int tid = threadIdx.x;
  for (int idx = tid; idx < 128 * 16; idx += 256) {
    int row = idx >> 4, slot = idx & 15;
    uint4 v = ((const uint4*)Wtb)[idx];
    *(uint4*)&Wlds[row * 68 + slot * 4] = v;
  }
  __syncthreads();

  const int lane = tid & 63, wid = tid >> 6;
  const int r0 = blockIdx.x * 128 + wid * 32;
  const int rowA = r0 + (lane & 15);
  const int kgrp = lane >> 4;
  const uint4* Abase = (const uint4*)Ab;

  f32x4 acc[2][8] = {};
#pragma unroll
  for (int kstep = 0; kstep < 4; ++kstep) {
    short8 a[2];
#pragma unroll
    for (int rb = 0; rb < 2; ++rb)
      a[rb] = as_short8(Abase[(size_t)(rowA + rb * 16) * 16 + kstep * 4 + kgrp]);
#pragma unroll
    for (int cb = 0; cb < 8; ++cb) {
      short8 b = as_short8(*(const uint4*)&Wlds[(cb * 16 + (lane & 15)) * 68 + (kstep * 4 + kgrp) * 4]);
      acc[0][cb] = __builtin_amdgcn_mfma_f32_16x16x32_bf16(a[0], b, acc[0][cb], 0, 0, 0);
      acc[1][cb] = __builtin_amdgcn_mfma_f32_16x16x32_bf16(a[1], b, acc[1][cb], 0, 0, 0);
    }
  }

  const int rbase = kgrp * 4;
#pragma unroll
  for (int cb = 0; cb < 8; ++cb) {
    int col = cb * 16 + (lane & 15);
    float bv = bias[col];
#pragma unroll
    for (int rb = 0; rb < 2; ++rb) {
#pragma unroll
      for (int i = 0; i < 4; ++i) {
        int row = r0 + rb * 16 + rbase + i;
        if (row < n) {
          float o = fmaxf(acc[rb][cb][i] + bv, 0.f);
          Hh[(size_t)row * 128 + col] = (unsigned short)bf16_rne(o);
        }
      }
    }
  }
}

// ---------- mean pool (bf16 in, fp32 out) ----------
__global__ __launch_bounds__(256) void pool_kernel(
    const unsigned int* __restrict__ Hb, const int* __restrict__ batch,
    float* __restrict__ gp, int n) {
  int g = blockIdx.x;
  int lo = 0, hi = n;
  while (lo < hi) { int mid = (lo + hi) >> 1; if (batch[mid] < g) lo = mid + 1; else hi = mid; }
  int start = lo;
  lo = start; hi = n;
  while (lo < hi) { int mid = (lo + hi) >> 1; if (batch[mid] < g + 1) lo = mid + 1; else hi = mid; }
  int end = lo;

  int lane = threadIdx.x & 63, grp = threadIdx.x >> 6;
  float s0 = 0.f, s1 = 0.f;
  for (int v = start + grp; v < end; v += 4) {
    unsigned int u = Hb[((size_t)v << 6) + lane];
    s0 += bf16lo(u);
    s1 += bf16hi(u);
  }
  __shared__ float red[4][128];
  red[grp][2 * lane] = s0;
  red[grp][2 * lane + 1] = s1;
  __syncthreads();
  if (threadIdx.x < 128) {
    float t = red[0][threadIdx.x] + red[1][threadIdx.x] + red[2][threadIdx.x] + red[3][threadIdx.x];
    float cnt = (float)(end - start);
    gp[g * 128 + threadIdx.x] = t / fmaxf(cnt, 1.0f);
  }
}

// ---------- context MLP + head fused (per-graph) ----------
__global__ __launch_bounds__(128) void ctx_head_kernel(
    const float* __restrict__ xc, const float* __restrict__ gp,
    const float* __restrict__ cW0, const float* __restrict__ cb0,
    const float* __restrict__ cW1, const float* __restrict__ cb1,
    const float* __restrict__ cW2, const float* __restrict__ cb2,
    const float* __restrict__ fW0, const float* __restrict__ fb0,
    const float* __restrict__ fW1, const float* __restrict__ fb1,
    const float* __restrict__ fW2, const float* __restrict__ fb2,
    float* __restrict__ out) {
  int g = blockIdx.x, c = threadIdx.x;
  __shared__ float xin[16];
  __shared__ float buf[128];
  __shared__ float z[256];

  if (c < 16) xin[c] = xc[g * 16 + c];
  __syncthreads();
  float a = cb0[c];
#pragma unroll
  for (int k = 0; k < 16; ++k) a += xin[k] * cW0[k * 128 + c];
  buf[c] = fmaxf(a, 0.f);
  __syncthreads();
  float a1 = cb1[c];
  for (int k = 0; k < 128; ++k) a1 += buf[k] * cW1[k * 128 + c];
  a1 = fmaxf(a1, 0.f);
  __syncthreads();
  buf[c] = a1;
  __syncthreads();
  float a2 = cb2[c];
  for (int k = 0; k < 128; ++k) a2 += buf[k] * cW2[k * 128 + c];
  a2 = fmaxf(a2, 0.f);

  // concat [gp, ctx]
  z[c] = gp[g * 128 + c];
  z[128 + c] = a2;
  __syncthreads();
  float h0 = fb0[c];
  for (int k = 0; k < 256; ++k) h0 += z[k] * fW0[k * 128 + c];
  h0 = fmaxf(h0, 0.f);
  __syncthreads();
  buf[c] = h0;
  __syncthreads();
  float h1 = fb1[c];
  for (int k = 0; k < 128; ++k) h1 += buf[k] * fW1[k * 128 + c];
  h1 = fmaxf(h1, 0.f);
  __syncthreads();
  buf[c] = h1;
  __syncthreads();
  float h2 = fb2[c];
  for (int k = 0; k < 128; ++k) h2 += buf[k] * fW2[k * 128 + c];
  out[g * 128 + c] = h2;
}

// ---------- launch ----------
extern "C" void kernel_launch(void* const* d_in, const int* in_sizes, int n_in,
                              void* d_out, int out_size, void* d_ws, size_t ws_size,
                              hipStream_t stream) {
  const float* x     = (const float*)d_in[0];
  const float* xc    = (const float*)d_in[1];
  const int*   ei    = (const int*)d_in[2];
  const int*   batch = (const int*)d_in[3];
  const float* ew    = (const float*)d_in[4];
  const float* gW[4] = {(const float*)d_in[5], (const float*)d_in[7], (const float*)d_in[9],  (const float*)d_in[11]};
  const float* gb[4] = {(const float*)d_in[6], (const float*)d_in[8], (const float*)d_in[10], (const float*)d_in[12]};
  const float* cW0 = (const float*)d_in[13]; const float* cb0 = (const float*)d_in[14];
  const float* cW1 = (const float*)d_in[15]; const float* cb1 = (const float*)d_in[16];
  const float* cW2 = (const float*)d_in[17]; const float* cb2 = (const float*)d_in[18];
  const float* fW0 = (const float*)d_in[19]; const float* fb0 = (const float*)d_in[20];
  const float* fW1 = (const float*)d_in[21]; const float* fb1 = (const float*)d_in[22];
  const float* fW2 = (const float*)d_in[23]; const float* fb2 = (const float*)d_in[24];
  float* out = (float*)d_out;

  const int N = in_sizes[3];
  const int E = in_sizes[4];
  const int G = in_sizes[1] / IN_CH;
  const int Np = (N + 127) & ~127;

  char* p = (char*)d_ws;
  auto alloc = [&](size_t bytes) { char* r = p; p += (bytes + 255) & ~(size_t)255; return r; };
  unsigned long long* packed = (unsigned long long*)alloc((size_t)N * 8);
  unsigned int* slot = (unsigned int*)alloc((size_t)E * 4);
  float* dinv     = (float*)alloc((size_t)N * 4);
  int*   row_ptr  = (int*)  alloc((size_t)(N + 1) * 4);
  int*   blocksum = (int*)  alloc((size_t)256 * 4);
  int2*  csr      = (int2*) alloc((size_t)E * 8);
  float* A0       = (float*)alloc((size_t)N * 16 * 4);
  unsigned int* Ab = (unsigned int*)alloc((size_t)Np * 64 * 4);
  unsigned int* Hb = (unsigned int*)alloc((size_t)Np * 64 * 4);
  unsigned int* Wt[3];
  for (int l = 0; l < 3; ++l) Wt[l] = (unsigned int*)alloc((size_t)128 * 64 * 4);
  float* gp = (float*)alloc((size_t)G * 128 * 4);

  int nbN = (N + 255) / 256;
  int nbE = (E + 255) / 256;
  int nbS = (N + 255) / 256;

  // CSR build (one atomic per edge, slot captured from return value)
  zero_kernel<<<256, 256, 0, stream>>>(packed, N);
  count_kernel<<<nbE, 256, 0, stream>>>(ei, ew, packed, slot, E);
  scan_block_kernel<<<nbS, 256, 0, stream>>>(packed, row_ptr, blocksum, dinv, N);
  scan_top_kernel<<<1, 256, 0, stream>>>(blocksum, nbS);
  scan_add_kernel<<<nbS, 256, 0, stream>>>(row_ptr, blocksum, N, E);
  scatter_kernel<<<nbE, 256, 0, stream>>>(ei, ew, dinv, row_ptr, slot, csr, E);

  // weight prep (layers 1-3)
  for (int l = 0; l < 3; ++l)
    prep_wt_kernel<<<32, 256, 0, stream>>>(gW[l + 1], Wt[l]);

  // layer 0
  spmm16_kernel<<<(N + 15) / 16, 256, 0, stream>>>(x, dinv, row_ptr, csr, A0, N);
  gemm16_kernel<<<(N + 31) / 32, 256, 0, stream>>>(A0, gW[0], gb[0], Hb, N);

  // layers 1-3
  for (int l = 0; l < 3; ++l) {
    spmm_bf16_kernel<<<(N + 3) / 4, 256, 0, stream>>>(Hb, dinv, row_ptr, csr, Ab, N);
    gemm_mfma_kernel<<<Np / 128, 256, 0, stream>>>(Ab, Wt[l], gb[l + 1], (unsigned short*)Hb, N);
  }

  // pool + context/head
  pool_kernel<<<G, 256, 0, stream>>>(Hb, batch, gp, N);
  ctx_head_kernel<<<G, 128, 0, stream>>>(xc, gp, cW0, cb0, cW1, cb1, cW2, cb2,
                                         fW0, fb0, fW1, fb1, fW2, fb2, out);
}

// Round 6
// 319.292 us; speedup vs baseline: 2.9390x; 1.2671x over previous
//
#include <hip/hip_runtime.h>

typedef __attribute__((ext_vector_type(8))) short short8;
typedef __attribute__((ext_vector_type(4))) float f32x4;

#define IN_CH 16
#define DEG_SCALE 1048576.0f           // 2^20 fixed point for weighted degree
#define DEG_MASK ((1ULL << 40) - 1)

// ---------- helpers ----------
__device__ inline unsigned int bf16_rne(float f) {
  unsigned int u = __float_as_uint(f);
  unsigned int r = u + 0x7fffu + ((u >> 16) & 1u);
  return r >> 16;
}
__device__ inline float bf16lo(unsigned int g) { return __uint_as_float(g << 16); }
__device__ inline float bf16hi(unsigned int g) { return __uint_as_float(g & 0xffff0000u); }
__device__ inline short8 as_short8(uint4 u) {
  union { uint4 u; short8 s; } cv; cv.u = u; return cv.s;
}

// ---------- zero packed counters ----------
__global__ void zero_kernel(unsigned long long* __restrict__ packed, int n) {
  int i = blockIdx.x * blockDim.x + threadIdx.x;
  for (int j = i; j < n; j += gridDim.x * blockDim.x) packed[j] = 0ULL;
}

// ---------- count: ONE 64-bit atomic per edge; return value gives slot ----------
__global__ void count_kernel(const int* __restrict__ ei, const float* __restrict__ ew,
                             unsigned long long* __restrict__ packed,
                             unsigned int* __restrict__ slot, int E) {
  int e = blockIdx.x * blockDim.x + threadIdx.x;
  if (e < E) {
    int dst = ei[E + e];
    unsigned long long inc =
        (1ULL << 40) | (unsigned long long)(unsigned int)(ew[e] * DEG_SCALE);
    unsigned long long old = atomicAdd(&packed[dst], inc);
    slot[e] = (unsigned int)(old >> 40);
  }
}

// ---------- scan (block stage): unpack counts, emit dinv, partial exclusive scan ----------
__global__ __launch_bounds__(256) void scan_block_kernel(
    const unsigned long long* __restrict__ packed,
    int* __restrict__ row_ptr, int* __restrict__ blocksum,
    float* __restrict__ dinv, int n) {
  int i = blockIdx.x * 256 + threadIdx.x;
  int v = 0;
  if (i < n) {
    unsigned long long pk = packed[i];
    v = (int)(pk >> 40);
    float d = 1.0f + (float)(pk & DEG_MASK) * (1.0f / DEG_SCALE);  // self loop + edge sum
    dinv[i] = rsqrtf(d);
  }
  int lane = threadIdx.x & 63;
  int incl = v;
#pragma unroll
  for (int off = 1; off < 64; off <<= 1) {
    int t = __shfl_up(incl, off);
    if (lane >= off) incl += t;
  }
  __shared__ int wsum[4];
  int w = threadIdx.x >> 6;
  if (lane == 63) wsum[w] = incl;
  __syncthreads();
  if (threadIdx.x == 0) {
    int a = wsum[0], b = wsum[1], c = wsum[2], d = wsum[3];
    wsum[0] = 0; wsum[1] = a; wsum[2] = a + b; wsum[3] = a + b + c;
    blocksum[blockIdx.x] = a + b + c + d;
  }
  __syncthreads();
  int excl = incl - v + wsum[w];
  if (i < n) row_ptr[i] = excl;
}

__global__ __launch_bounds__(256) void scan_top_kernel(int* __restrict__ blocksum, int nb) {
  int v = (threadIdx.x < nb) ? blocksum[threadIdx.x] : 0;
  int lane = threadIdx.x & 63;
  int incl = v;
#pragma unroll
  for (int off = 1; off < 64; off <<= 1) {
    int t = __shfl_up(incl, off);
    if (lane >= off) incl += t;
  }
  __shared__ int wsum[4];
  int w = threadIdx.x >> 6;
  if (lane == 63) wsum[w] = incl;
  __syncthreads();
  if (threadIdx.x == 0) {
    int a = wsum[0], b = wsum[1], c = wsum[2];
    wsum[3] = a + b + c; wsum[2] = a + b; wsum[1] = a; wsum[0] = 0;
  }
  __syncthreads();
  int excl = incl - v + wsum[w];
  if (threadIdx.x < nb) blocksum[threadIdx.x] = excl;
}

__global__ __launch_bounds__(256) void scan_add_kernel(int* __restrict__ row_ptr,
                                                       const int* __restrict__ blocksum,
                                                       int n, int E) {
  int i = blockIdx.x * 256 + threadIdx.x;
  if (i < n) row_ptr[i] += blocksum[blockIdx.x];
  if (i == 0) row_ptr[n] = E;
}

// ---------- scatter: NO atomics (slot precomputed) ----------
__global__ void scatter_kernel(const int* __restrict__ ei, const float* __restrict__ ew,
                               const float* __restrict__ dinv, const int* __restrict__ row_ptr,
                               const unsigned int* __restrict__ slot,
                               int2* __restrict__ csr, int E) {
  int e = blockIdx.x * blockDim.x + threadIdx.x;
  if (e < E) {
    int src = ei[e];
    int dst = ei[E + e];
    int pos = row_ptr[dst] + (int)slot[e];
    int2 p;
    p.x = src;
    p.y = __float_as_int(ew[e] * dinv[src]);
    csr[pos] = p;
  }
}

// ---------- SpMM layer0: fp32, 16ch, 16 lanes/node ----------
__global__ __launch_bounds__(256) void spmm16_kernel(
    const float* __restrict__ x, const float* __restrict__ dinv,
    const int* __restrict__ row_ptr, const int2* __restrict__ csr,
    float* __restrict__ A0, int n) {
  int lane = threadIdx.x & 15;
  int v = blockIdx.x * 16 + (threadIdx.x >> 4);
  if (v >= n) return;
  int beg = row_ptr[v], end = row_ptr[v + 1];
  float sum = 0.f;
  for (int e = beg; e < end; e += 8) {
#pragma unroll
    for (int i = 0; i < 8; ++i) {
      int ee = e + i;
      bool ok = ee < end;
      int2 p = csr[ok ? ee : beg];
      float w = ok ? __int_as_float(p.y) : 0.f;
      sum += w * x[(size_t)p.x * 16 + lane];
    }
  }
  float dv = dinv[v];
  float self = x[(size_t)v * 16 + lane];
  A0[(size_t)v * 16 + lane] = dv * sum + dv * dv * self;
}

// ---------- SpMM layers 1-3: bf16, 4 edges per wave via uint4 lanes ----------
// lane layout: q = lane>>4 (edge within quad-group), c = lane&15 (channels 8c..8c+7)
__global__ __launch_bounds__(256) void spmm_bf16_kernel(
    const uint4* __restrict__ Hb4, const float* __restrict__ dinv,
    const int* __restrict__ row_ptr, const int2* __restrict__ csr,
    uint4* __restrict__ Ab4, int n) {
  const int l = threadIdx.x & 63;
  const int q = l >> 4;
  const int c = l & 15;
  const int v = (blockIdx.x << 2) + (threadIdx.x >> 6);
  if (v >= n) return;
  const int beg = row_ptr[v], end = row_ptr[v + 1];
  float s[8] = {};
  for (int e = beg; e < end; e += 16) {
#pragma unroll
    for (int i = 0; i < 4; ++i) {
      int ee = e + i * 4 + q;
      bool ok = ee < end;
      int2 p = csr[ok ? ee : beg];
      float w = ok ? __int_as_float(p.y) : 0.f;
      uint4 u = Hb4[(size_t)p.x * 16 + c];
      s[0] += w * bf16lo(u.x); s[1] += w * bf16hi(u.x);
      s[2] += w * bf16lo(u.y); s[3] += w * bf16hi(u.y);
      s[4] += w * bf16lo(u.z); s[5] += w * bf16hi(u.z);
      s[6] += w * bf16lo(u.w); s[7] += w * bf16hi(u.w);
    }
  }
  // combine the 4 quad partial sums (butterfly: all lanes end with total)
#pragma unroll
  for (int j = 0; j < 8; ++j) {
    s[j] += __shfl_xor(s[j], 16);
    s[j] += __shfl_xor(s[j], 32);
  }
  float dv = dinv[v];
  float dv2 = dv * dv;
  uint4 self = Hb4[(size_t)v * 16 + c];
  float r0 = dv * s[0] + dv2 * bf16lo(self.x);
  float r1 = dv * s[1] + dv2 * bf16hi(self.x);
  float r2 = dv * s[2] + dv2 * bf16lo(self.y);
  float r3 = dv * s[3] + dv2 * bf16hi(self.y);
  float r4 = dv * s[4] + dv2 * bf16lo(self.z);
  float r5 = dv * s[5] + dv2 * bf16hi(self.z);
  float r6 = dv * s[6] + dv2 * bf16lo(self.w);
  float r7 = dv * s[7] + dv2 * bf16hi(self.w);
  if (q == 0) {
    uint4 o;
    o.x = bf16_rne(r0) | (bf16_rne(r1) << 16);
    o.y = bf16_rne(r2) | (bf16_rne(r3) << 16);
    o.z = bf16_rne(r4) | (bf16_rne(r5) << 16);
    o.w = bf16_rne(r6) | (bf16_rne(r7) << 16);
    Ab4[(size_t)v * 16 + c] = o;
  }
}

// ---------- GEMM layer0: fp32 X[n,16] @ W[16,128] + b, relu, bf16 out ----------
__global__ __launch_bounds__(256) void gemm16_kernel(
    const float* __restrict__ X, const float* __restrict__ W,
    const float* __restrict__ bias, unsigned int* __restrict__ Hb, int n) {
  __shared__ float Ws[16][128];
  __shared__ float Xs[32][16];
  const int tid = threadIdx.x;
  const int row0 = blockIdx.x * 32;

  for (int i = tid * 4; i < 16 * 128; i += 1024)
    *(float4*)&Ws[0][i] = *(const float4*)&W[i];
  for (int i = tid * 4; i < 32 * 16; i += 1024) {
    int r = i / 16, k = i % 16;
    int rr = row0 + r;
    float4 v = make_float4(0.f, 0.f, 0.f, 0.f);
    if (rr < n) v = *(const float4*)&X[(size_t)rr * 16 + k];
    *(float4*)&Xs[r][k] = v;
  }
  __syncthreads();

  const int tc = (tid & 31) * 4;
  const int tr = (tid >> 5) * 4;
  float acc[4][4] = {};
  for (int k = 0; k < 16; k += 4) {
    float4 xv[4];
#pragma unroll
    for (int r = 0; r < 4; ++r) xv[r] = *(const float4*)&Xs[tr + r][k];
    float4 wv[4];
#pragma unroll
    for (int kk = 0; kk < 4; ++kk) wv[kk] = *(const float4*)&Ws[k + kk][tc];
#pragma unroll
    for (int r = 0; r < 4; ++r) {
      float xr[4] = {xv[r].x, xv[r].y, xv[r].z, xv[r].w};
#pragma unroll
      for (int kk = 0; kk < 4; ++kk) {
        acc[r][0] += xr[kk] * wv[kk].x;
        acc[r][1] += xr[kk] * wv[kk].y;
        acc[r][2] += xr[kk] * wv[kk].z;
        acc[r][3] += xr[kk] * wv[kk].w;
      }
    }
  }

  float4 bv = *(const float4*)&bias[tc];
#pragma unroll
  for (int r = 0; r < 4; ++r) {
    int rr = row0 + tr + r;
    if (rr < n) {
      float o0 = fmaxf(acc[r][0] + bv.x, 0.f);
      float o1 = fmaxf(acc[r][1] + bv.y, 0.f);
      float o2 = fmaxf(acc[r][2] + bv.z, 0.f);
      float o3 = fmaxf(acc[r][3] + bv.w, 0.f);
      uint2 st;
      st.x = bf16_rne(o0) | (bf16_rne(o1) << 16);
      st.y = bf16_rne(o2) | (bf16_rne(o3) << 16);
      *(uint2*)&Hb[(size_t)rr * 64 + (tc >> 1)] = st;
    }
  }
}

// ---------- weight prep: fp32 W[k][c] -> packed bf16 Wt[c][kpair] ----------
__global__ void prep_wt_kernel(const float* __restrict__ W, unsigned int* __restrict__ Wt) {
  int idx = blockIdx.x * 256 + threadIdx.x;
  if (idx >= 128 * 64) return;
  int c = idx >> 6, kp = idx & 63;
  float f0 = W[(2 * kp) * 128 + c];
  float f1 = W[(2 * kp + 1) * 128 + c];
  Wt[idx] = bf16_rne(f0) | (bf16_rne(f1) << 16);
}

// ---------- MFMA GEMM: bf16 A[n,128] @ W[128,128] + b, relu, bf16 out ----------
__global__ __launch_bounds__(256) void gemm_mfma_kernel(
    const unsigned int* __restrict__ Ab, const unsigned int* __restrict__ Wtb,
    const float* __restrict__ bias, unsigned short* __restrict__ Hh, int n) {
  __shared__ unsigned int Wlds[128 * 68];  // row stride 68 uints = 272B (16B pad)
  const int tid = threadIdx.x;
  for (int idx = tid; idx < 128 * 16; idx += 256) {
    int row = idx >> 4, slot = idx & 15;
    uint4 v = ((const uint4*)Wtb)[idx];
    *(uint4*)&Wlds[row * 68 + slot * 4] = v;
  }
  __syncthreads();

  const int lane = tid & 63, wid = tid >> 6;
  const int r0 = blockIdx.x * 128 + wid * 32;
  const int rowA = r0 + (lane & 15);
  const int kgrp = lane >> 4;
  const uint4* Abase = (const uint4*)Ab;

  f32x4 acc[2][8] = {};
#pragma unroll
  for (int kstep = 0; kstep < 4; ++kstep) {
    short8 a[2];
#pragma unroll
    for (int rb = 0; rb < 2; ++rb)
      a[rb] = as_short8(Abase[(size_t)(rowA + rb * 16) * 16 + kstep * 4 + kgrp]);
#pragma unroll
    for (int cb = 0; cb < 8; ++cb) {
      short8 b = as_short8(*(const uint4*)&Wlds[(cb * 16 + (lane & 15)) * 68 + (kstep * 4 + kgrp) * 4]);
      acc[0][cb] = __builtin_amdgcn_mfma_f32_16x16x32_bf16(a[0], b, acc[0][cb], 0, 0, 0);
      acc[1][cb] = __builtin_amdgcn_mfma_f32_16x16x32_bf16(a[1], b, acc[1][cb], 0, 0, 0);
    }
  }

  const int rbase = kgrp * 4;
#pragma unroll
  for (int cb = 0; cb < 8; ++cb) {
    int col = cb * 16 + (lane & 15);
    float bv = bias[col];
#pragma unroll
    for (int rb = 0; rb < 2; ++rb) {
#pragma unroll
      for (int i = 0; i < 4; ++i) {
        int row = r0 + rb * 16 + rbase + i;
        if (row < n) {
          float o = fmaxf(acc[rb][cb][i] + bv, 0.f);
          Hh[(size_t)row * 128 + col] = (unsigned short)bf16_rne(o);
        }
      }
    }
  }
}

// ---------- mean pool (bf16 in, fp32 out) ----------
__global__ __launch_bounds__(256) void pool_kernel(
    const unsigned int* __restrict__ Hb, const int* __restrict__ batch,
    float* __restrict__ gp, int n) {
  int g = blockIdx.x;
  int lo = 0, hi = n;
  while (lo < hi) { int mid = (lo + hi) >> 1; if (batch[mid] < g) lo = mid + 1; else hi = mid; }
  int start = lo;
  lo = start; hi = n;
  while (lo < hi) { int mid = (lo + hi) >> 1; if (batch[mid] < g + 1) lo = mid + 1; else hi = mid; }
  int end = lo;

  int lane = threadIdx.x & 63, grp = threadIdx.x >> 6;
  float s0 = 0.f, s1 = 0.f;
  for (int v = start + grp; v < end; v += 4) {
    unsigned int u = Hb[((size_t)v << 6) + lane];
    s0 += bf16lo(u);
    s1 += bf16hi(u);
  }
  __shared__ float red[4][128];
  red[grp][2 * lane] = s0;
  red[grp][2 * lane + 1] = s1;
  __syncthreads();
  if (threadIdx.x < 128) {
    float t = red[0][threadIdx.x] + red[1][threadIdx.x] + red[2][threadIdx.x] + red[3][threadIdx.x];
    float cnt = (float)(end - start);
    gp[g * 128 + threadIdx.x] = t / fmaxf(cnt, 1.0f);
  }
}

// ---------- context MLP + head fused (per-graph) ----------
__global__ __launch_bounds__(128) void ctx_head_kernel(
    const float* __restrict__ xc, const float* __restrict__ gp,
    const float* __restrict__ cW0, const float* __restrict__ cb0,
    const float* __restrict__ cW1, const float* __restrict__ cb1,
    const float* __restrict__ cW2, const float* __restrict__ cb2,
    const float* __restrict__ fW0, const float* __restrict__ fb0,
    const float* __restrict__ fW1, const float* __restrict__ fb1,
    const float* __restrict__ fW2, const float* __restrict__ fb2,
    float* __restrict__ out) {
  int g = blockIdx.x, c = threadIdx.x;
  __shared__ float xin[16];
  __shared__ float buf[128];
  __shared__ float z[256];

  if (c < 16) xin[c] = xc[g * 16 + c];
  __syncthreads();
  float a = cb0[c];
#pragma unroll
  for (int k = 0; k < 16; ++k) a += xin[k] * cW0[k * 128 + c];
  buf[c] = fmaxf(a, 0.f);
  __syncthreads();
  float a1 = cb1[c];
  for (int k = 0; k < 128; ++k) a1 += buf[k] * cW1[k * 128 + c];
  a1 = fmaxf(a1, 0.f);
  __syncthreads();
  buf[c] = a1;
  __syncthreads();
  float a2 = cb2[c];
  for (int k = 0; k < 128; ++k) a2 += buf[k] * cW2[k * 128 + c];
  a2 = fmaxf(a2, 0.f);

  // concat [gp, ctx]
  z[c] = gp[g * 128 + c];
  z[128 + c] = a2;
  __syncthreads();
  float h0 = fb0[c];
  for (int k = 0; k < 256; ++k) h0 += z[k] * fW0[k * 128 + c];
  h0 = fmaxf(h0, 0.f);
  __syncthreads();
  buf[c] = h0;
  __syncthreads();
  float h1 = fb1[c];
  for (int k = 0; k < 128; ++k) h1 += buf[k] * fW1[k * 128 + c];
  h1 = fmaxf(h1, 0.f);
  __syncthreads();
  buf[c] = h1;
  __syncthreads();
  float h2 = fb2[c];
  for (int k = 0; k < 128; ++k) h2 += buf[k] * fW2[k * 128 + c];
  out[g * 128 + c] = h2;
}

// ---------- launch ----------
extern "C" void kernel_launch(void* const* d_in, const int* in_sizes, int n_in,
                              void* d_out, int out_size, void* d_ws, size_t ws_size,
                              hipStream_t stream) {
  const float* x     = (const float*)d_in[0];
  const float* xc    = (const float*)d_in[1];
  const int*   ei    = (const int*)d_in[2];
  const int*   batch = (const int*)d_in[3];
  const float* ew    = (const float*)d_in[4];
  const float* gW[4] = {(const float*)d_in[5], (const float*)d_in[7], (const float*)d_in[9],  (const float*)d_in[11]};
  const float* gb[4] = {(const float*)d_in[6], (const float*)d_in[8], (const float*)d_in[10], (const float*)d_in[12]};
  const float* cW0 = (const float*)d_in[13]; const float* cb0 = (const float*)d_in[14];
  const float* cW1 = (const float*)d_in[15]; const float* cb1 = (const float*)d_in[16];
  const float* cW2 = (const float*)d_in[17]; const float* cb2 = (const float*)d_in[18];
  const float* fW0 = (const float*)d_in[19]; const float* fb0 = (const float*)d_in[20];
  const float* fW1 = (const float*)d_in[21]; const float* fb1 = (const float*)d_in[22];
  const float* fW2 = (const float*)d_in[23]; const float* fb2 = (const float*)d_in[24];
  float* out = (float*)d_out;

  const int N = in_sizes[3];
  const int E = in_sizes[4];
  const int G = in_sizes[1] / IN_CH;
  const int Np = (N + 127) & ~127;

  char* p = (char*)d_ws;
  auto alloc = [&](size_t bytes) { char* r = p; p += (bytes + 255) & ~(size_t)255; return r; };
  unsigned long long* packed = (unsigned long long*)alloc((size_t)N * 8);
  unsigned int* slot = (unsigned int*)alloc((size_t)E * 4);
  float* dinv     = (float*)alloc((size_t)N * 4);
  int*   row_ptr  = (int*)  alloc((size_t)(N + 1) * 4);
  int*   blocksum = (int*)  alloc((size_t)256 * 4);
  int2*  csr      = (int2*) alloc((size_t)E * 8);
  float* A0       = (float*)alloc((size_t)N * 16 * 4);
  unsigned int* Ab = (unsigned int*)alloc((size_t)Np * 64 * 4);
  unsigned int* Hb = (unsigned int*)alloc((size_t)Np * 64 * 4);
  unsigned int* Wt[3];
  for (int l = 0; l < 3; ++l) Wt[l] = (unsigned int*)alloc((size_t)128 * 64 * 4);
  float* gp = (float*)alloc((size_t)G * 128 * 4);

  int nbN = (N + 255) / 256;
  int nbE = (E + 255) / 256;
  int nbS = (N + 255) / 256;

  // CSR build (one atomic per edge, slot captured from return value)
  zero_kernel<<<256, 256, 0, stream>>>(packed, N);
  count_kernel<<<nbE, 256, 0, stream>>>(ei, ew, packed, slot, E);
  scan_block_kernel<<<nbS, 256, 0, stream>>>(packed, row_ptr, blocksum, dinv, N);
  scan_top_kernel<<<1, 256, 0, stream>>>(blocksum, nbS);
  scan_add_kernel<<<nbS, 256, 0, stream>>>(row_ptr, blocksum, N, E);
  scatter_kernel<<<nbE, 256, 0, stream>>>(ei, ew, dinv, row_ptr, slot, csr, E);

  // weight prep (layers 1-3)
  for (int l = 0; l < 3; ++l)
    prep_wt_kernel<<<32, 256, 0, stream>>>(gW[l + 1], Wt[l]);

  // layer 0
  spmm16_kernel<<<(N + 15) / 16, 256, 0, stream>>>(x, dinv, row_ptr, csr, A0, N);
  gemm16_kernel<<<(N + 31) / 32, 256, 0, stream>>>(A0, gW[0], gb[0], Hb, N);

  // layers 1-3
  for (int l = 0; l < 3; ++l) {
    spmm_bf16_kernel<<<(N + 3) / 4, 256, 0, stream>>>((const uint4*)Hb, dinv, row_ptr, csr,
                                                      (uint4*)Ab, N);
    gemm_mfma_kernel<<<Np / 128, 256, 0, stream>>>(Ab, Wt[l], gb[l + 1], (unsigned short*)Hb, N);
  }

  // pool + context/head
  pool_kernel<<<G, 256, 0, stream>>>(Hb, batch, gp, N);
  ctx_head_kernel<<<G, 128, 0, stream>>>(xc, gp, cW0, cb0, cW1, cb1, cW2, cb2,
                                         fW0, fb0, fW1, fb1, fW2, fb2, out);
}